// Round 13
// baseline (129.125 us; speedup 1.0000x reference)
//
#include <hip/hip_runtime.h>
#include <math.h>

typedef unsigned short u16;
typedef unsigned int u32;
typedef __attribute__((ext_vector_type(8))) short short8;
typedef __attribute__((ext_vector_type(8))) u16 u16x8;
typedef __attribute__((ext_vector_type(4))) float f32x4;

#define PH(i) ((i) + ((i) >> 4))

#if __has_builtin(__builtin_amdgcn_rcpf)
#define RCP(x) __builtin_amdgcn_rcpf(x)
#else
#define RCP(x) (1.0f / (x))
#endif

static __device__ __forceinline__ u16 f2bf(float x) {
  unsigned u = __builtin_bit_cast(unsigned, x);
  return (u16)((u + 0x7FFFu + ((u >> 16) & 1u)) >> 16);
}

static __device__ __forceinline__ float2 cmul(float2 a, float2 b) {
  return make_float2(a.x * b.x - a.y * b.y, a.x * b.y + a.y * b.x);
}
static __device__ __forceinline__ float2 cadd(float2 a, float2 b) {
  return make_float2(a.x + b.x, a.y + b.y);
}
static __device__ __forceinline__ float2 conjf2(float2 a) {
  return make_float2(a.x, -a.y);
}

// tanh-form GELU: y * sigmoid(1.59577*(y + 0.044715 y^3)); max dev ~1e-3
static __device__ __forceinline__ float gelu_fast(float y) {
  const float t = __builtin_fmaf(0.044715f * y * y, y, y);
  const float e = __expf(-1.5957691216f * t);
  return y * RCP(1.f + e);
}

static __device__ __forceinline__ u32 pack_out(float2 r) {
  const u32 lo = f2bf(gelu_fast(r.x));
  const u32 hi = f2bf(gelu_fast(-r.y));
  return lo | (hi << 16);
}

// async global->LDS, 16B per lane
static __device__ __forceinline__ void gload_lds16(const void* g, void* l) {
  __builtin_amdgcn_global_load_lds(
      (const __attribute__((address_space(1))) u32*)g,
      (__attribute__((address_space(3))) u32*)l, 16, 0, 0);
}

#define BF4(A, B, C, D, Y0, Y1, Y2, Y3)                                        \
  {                                                                            \
    const float apcr = (A).x + (C).x, apci = (A).y + (C).y;                    \
    const float amcr = (A).x - (C).x, amci = (A).y - (C).y;                    \
    const float bpdr = (B).x + (D).x, bpdi = (B).y + (D).y;                    \
    const float bmdr = (B).x - (D).x, bmdi = (B).y - (D).y;                    \
    Y0 = make_float2(apcr + bpdr, apci + bpdi);                                \
    Y2 = make_float2(apcr - bpdr, apci - bpdi);                                \
    Y1 = make_float2(amcr + bmdi, amci - bmdr);                                \
    Y3 = make_float2(amcr - bmdi, amci + bmdr);                                \
  }

// ---------------- K1: merged hope-kernel + filter coeffs (+D folded) + W->bf16
static __device__ __forceinline__ void hope_sum(
    const float* __restrict__ log_dt, const float* __restrict__ Hr,
    const float* __restrict__ Hi, int h, int l, float* outr, float* outi) {
  const float dt = expf(log_dt[h]);
  const float phi = 6.28318530717958647692f * (float)l * (1.0f / 1024.0f);
  float sphi, cphi;
  sincosf(phi, &sphi, &cphi);
  const float nr = (1.f + dt) * cphi + dt - 1.f;
  const float ni = (1.f + dt) * sphi;
  const float dr = (dt - 1.f) * cphi + dt + 1.f;
  const float di = (dt - 1.f) * sphi;
  const float theta = atan2f(ni * dr - nr * di, nr * dr + ni * di);
  float sw, cw;
  sincosf(theta, &sw, &cw);
  const float wr = cw, wi = -sw;  // e^{-i theta}
  float cr = wr, ci = wi;
  float ar = 0.f, ai = 0.f;
  const float* __restrict__ hr = Hr + h * 64;
  const float* __restrict__ hi = Hi + h * 64;
  for (int n = 0; n < 64; ++n) {
    const float a = hr[n], bb = hi[n];
    ar += a * cr - bb * ci;
    ai += a * ci + bb * cr;
    const float t = cr * wr - ci * wi;
    ci = cr * wi + ci * wr;
    cr = t;
  }
  *outr = ar;
  *outi = ai;
}

__global__ __launch_bounds__(512) void build_kep(
    const float* __restrict__ log_dt, const float* __restrict__ Hr,
    const float* __restrict__ Hi, const float* __restrict__ Dv,
    const float* __restrict__ W, float2* __restrict__ kep,
    u16* __restrict__ Wb) {
  __shared__ float2 K1[1024], K2[1024];
  const int c = blockIdx.x;
  const int t = threadIdx.x;
  // fold conv_w in: block c converts W[c*1024 .. c*1024+1024)
  Wb[c * 1024 + t] = f2bf(W[c * 1024 + t]);
  Wb[c * 1024 + 512 + t] = f2bf(W[c * 1024 + 512 + t]);
  float r, i;
  hope_sum(log_dt, Hr, Hi, c, t, &r, &i);             K1[t] = make_float2(r, i);
  hope_sum(log_dt, Hr, Hi, c, t + 512, &r, &i);       K1[t + 512] = make_float2(r, i);
  hope_sum(log_dt, Hr, Hi, c + 512, t, &r, &i);       K2[t] = make_float2(r, i);
  hope_sum(log_dt, Hr, Hi, c + 512, t + 512, &r, &i); K2[t + 512] = make_float2(r, i);
  __syncthreads();
  const float s = 1.0f / 2048.0f;   // fold ifft scale (exact)
  const float dcs = Dv[c] * s;      // fold D-skip: k'[f] = k[f] + D[c]
  for (int q = t; q <= 512; q += 512) {  // t==0 also covers q=512
    float2 kf, kg;
    {
      const int qa = q;
      kf = (qa == 0) ? make_float2(K1[0].x * s, 0.f)
                     : make_float2(0.5f * s * (K1[qa].x + K2[qa - 1].x),
                                   0.5f * s * (K1[qa].y - K2[qa - 1].y));
      const int qb = 1024 - q;
      kg = (qb == 1024) ? make_float2(K2[1023].x * s, 0.f)
           : (qb == 0)  ? make_float2(K1[0].x * s, 0.f)
                        : make_float2(0.5f * s * (K1[qb].x + K2[qb - 1].x),
                                      0.5f * s * (K1[qb].y - K2[qb - 1].y));
    }
    kf.x += dcs;
    kg.x += dcs;
    float2 C1, C2, C3, C4;
    if (q == 0) {
      C1 = make_float2(kf.x + kg.x, kg.y - kf.y);
      C2 = make_float2(-(kg.y + kf.y), kg.x - kf.x);
      C3 = C2;
      C4 = C1;
    } else {
      float st, ct;
      sincosf(3.14159265358979323846f * (float)q * (1.f / 1024.f), &st, &ct);
      const float2 A1 = make_float2(1.f - st, -ct);
      const float2 A2 = make_float2(1.f + st, ct);
      const float2 kgc = make_float2(kg.x, -kg.y);
      const float2 t1 = cmul(kf, A1), t2 = cmul(kgc, A2);
      const float2 t3 = cmul(kf, A2), t4 = cmul(kgc, A1);
      const float2 p1 = make_float2(0.5f * (t1.x + t2.x), 0.5f * (t1.y + t2.y));
      const float2 p2 = make_float2(0.5f * (t3.x + t4.x), 0.5f * (t3.y + t4.y));
      const float2 q1 = make_float2(0.5f * (t1.x - t2.x), 0.5f * (t1.y - t2.y));
      const float2 q2 = make_float2(0.5f * (t3.x - t4.x), 0.5f * (t3.y - t4.y));
      const float2 iWc = make_float2(-st, ct);
      const float2 r1 = cmul(iWc, q1), r2 = cmul(iWc, q2);
      C1 = make_float2(p1.x + r1.x, -(p1.y + r1.y));
      C2 = make_float2(p2.x + r2.x, -(p2.y + r2.y));
      C3 = make_float2(p1.x - r1.x, p1.y - r1.y);
      C4 = make_float2(p2.x - r2.x, p2.y - r2.y);
    }
    float2* o = kep + ((size_t)c * 513 + q) * 4;
    o[0] = C1; o[1] = C2; o[2] = C3; o[3] = C4;
  }
}

// ---------------- K2: wave-autonomous fused radix-16 rfft-conv ----------------
// One WAVE per 1024-pt FFT row (beta = lane). All LDS sharing is intra-wave ->
// lockstep program order (reads precede writes) makes barriers unnecessary.
// Verified math from R11 (refcheck'd); verified ordering from R6 (refcheck'd).
static __device__ __forceinline__ void radix16(
    const float2* __restrict__ v, float2* __restrict__ o,
    const float2* __restrict__ wk, float2 W1) {
  float2 s[4][4];
  #pragma unroll
  for (int k = 0; k < 4; ++k) {
    float2 y0, y1, y2, y3;
    BF4(v[k], v[k + 4], v[k + 8], v[k + 12], y0, y1, y2, y3);
    const float2 w1 = wk[k];
    const float2 w2 = cmul(w1, w1);
    const float2 w3 = cmul(w2, w1);
    s[0][k] = y0;
    s[1][k] = cmul(w1, y1);
    s[2][k] = cmul(w2, y2);
    s[3][k] = cmul(w3, y3);
  }
  const float2 W2 = cmul(W1, W1);
  const float2 W3 = cmul(W2, W1);
  #pragma unroll
  for (int q = 0; q < 4; ++q) {
    float2 z0, z1, z2, z3;
    BF4(s[q][0], s[q][1], s[q][2], s[q][3], z0, z1, z2, z3);
    o[q] = z0;
    o[q + 4] = cmul(W1, z1);
    o[q + 8] = cmul(W2, z2);
    o[q + 12] = cmul(W3, z3);
  }
}

// pass B (stages m=16,64): in-place, intra-wave (no barrier)
static __device__ __forceinline__ void passB(float2* __restrict__ D, int beta,
                                             const float2* __restrict__ twl) {
  float2 v[16], o[16], wk[4];
  #pragma unroll
  for (int j = 0; j < 16; ++j) v[j] = D[PH(beta + 64 * j)];
  #pragma unroll
  for (int k = 0; k < 4; ++k) wk[k] = twl[(beta & 48) + 64 * k];
  radix16(v, o, wk, twl[(beta >> 4) * 64]);
  const int base = 256 * (beta >> 4) + (beta & 15);
  #pragma unroll
  for (int qp = 0; qp < 4; ++qp)
    #pragma unroll
    for (int q = 0; q < 4; ++q)
      D[PH(base + 16 * q + 64 * qp)] = o[q + 4 * qp];
}

// pass A for FFT#2 (LDS source): in-place, intra-wave (no barrier)
static __device__ __forceinline__ void passA2(float2* __restrict__ D, int beta,
                                              const float2* __restrict__ twl) {
  float2 v[16], o[16], wk[4];
  #pragma unroll
  for (int j = 0; j < 16; ++j) v[j] = D[PH(beta + 64 * j)];
  #pragma unroll
  for (int k = 0; k < 4; ++k) wk[k] = twl[beta + 64 * k];
  radix16(v, o, wk, twl[4 * beta]);
  #pragma unroll
  for (int x = 0; x < 16; ++x) D[PH(16 * beta + x)] = o[x];
}

__global__ __launch_bounds__(512, 2) void fft_conv(
    const float* __restrict__ u, const float2* __restrict__ kep,
    u16* __restrict__ y) {
  __shared__ __align__(16) float2 dat[8][1088];  // 69632 B
  __shared__ float2 twl[256];                    //  2048 B -> ~71.7 KB
  const int t = threadIdx.x;
  const int beta = t & 63, r = t >> 6;           // one wave per row
  if (t < 256) {
    float s0, c0;
    __sincosf(6.28318530717958647692f * (float)t * (1.f / 1024.f), &s0, &c0);
    twl[t] = make_float2(c0, -s0);
  }
  __syncthreads();  // ONLY barrier: twl visible to all 8 waves

  const int bq = blockIdx.x, c = blockIdx.y;
  const int b = bq * 8 + r;
  const float2* __restrict__ u2 = (const float2*)(u + ((size_t)(b * 512 + c)) * 2048);
  u32* __restrict__ yr = (u32*)(y + ((size_t)(b * 512 + c)) * 2048);
  const float4* __restrict__ krow4 = (const float4*)(kep + (size_t)c * (513 * 4));
  float2* __restrict__ D = dat[r];

  // FFT1 pass A (m=1,4), inputs from global: z[p] = u[2p] + i u[2p+1]
  {
    float2 va[16], o[16], wk[4];
    #pragma unroll
    for (int j = 0; j < 16; ++j) va[j] = u2[beta + 64 * j];
    #pragma unroll
    for (int k = 0; k < 4; ++k) wk[k] = twl[beta + 64 * k];
    radix16(va, o, wk, twl[4 * beta]);
    #pragma unroll
    for (int x = 0; x < 16; ++x) D[PH(16 * beta + x)] = o[x];
  }
  passB(D, beta, twl);

  // FFT1 pass C (m=256, twiddle-free; self-in-place) + keep Zf low half in regs
  float2 zf[8];
  {
    float2 v[16], o[16];
    #pragma unroll
    for (int j = 0; j < 16; ++j) v[j] = D[PH(beta + 64 * j)];
    #pragma unroll
    for (int k = 0; k < 4; ++k)
      BF4(v[k], v[k + 4], v[k + 8], v[k + 12], o[k], o[k + 4], o[k + 8], o[k + 12]);
    #pragma unroll
    for (int j = 0; j < 8; ++j) zf[j] = o[j];
    #pragma unroll
    for (int j = 8; j < 16; ++j) D[PH(beta + 64 * j)] = o[j];  // high half only
  }

  // filter: pairs (f, 1024-f); reads all precede writes (intra-wave lockstep)
  {
    float2 Df[8], Dg[8], D5;
    #pragma unroll
    for (int j = 0; j < 8; ++j) {
      const int f = beta + 64 * j;
      const float4 A4 = krow4[2 * f];
      const float4 B4 = krow4[2 * f + 1];
      const float2 C1 = make_float2(A4.x, A4.y), C2 = make_float2(A4.z, A4.w);
      const float2 C3 = make_float2(B4.x, B4.y), C4 = make_float2(B4.z, B4.w);
      const float2 Zf = zf[j];
      const float2 Zg = (f == 0) ? zf[0] : D[PH(1024 - f)];
      Df[j] = cadd(cmul(C1, conjf2(Zf)), cmul(C2, Zg));
      Dg[j] = cadd(cmul(C3, Zf), cmul(C4, conjf2(Zg)));
    }
    if (beta == 0) {
      const float4 M = krow4[1024];
      const float2 C1 = make_float2(M.x, M.y), C2 = make_float2(M.z, M.w);
      const float2 Z5 = D[PH(512)];  // written by own lane in pass C
      D5 = cadd(cmul(C1, conjf2(Z5)), cmul(C2, Z5));
    }
    #pragma unroll
    for (int j = 0; j < 8; ++j) {
      const int f = beta + 64 * j;
      D[PH(f)] = Df[j];
      D[PH((1024 - f) & 1023)] = Dg[j];
    }
    if (beta == 0) D[PH(512)] = D5;
  }

  passA2(D, beta, twl);  // FFT2 (inverse via conj trick)
  passB(D, beta, twl);

  // FFT2 pass C + GELU + store (D-skip folded into kep)
  {
    float2 v[16], o[16];
    #pragma unroll
    for (int j = 0; j < 16; ++j) v[j] = D[PH(beta + 64 * j)];
    #pragma unroll
    for (int k = 0; k < 4; ++k)
      BF4(v[k], v[k + 4], v[k + 8], v[k + 12], o[k], o[k + 4], o[k + 8], o[k + 12]);
    #pragma unroll
    for (int j = 0; j < 16; ++j) yr[beta + 64 * j] = pack_out(o[j]);
  }
}

// ---------------- K2b: y (B,C,L) bf16 -> yt (B,L,C) bf16 ----------------
__global__ __launch_bounds__(256) void transpose_y(
    const u16* __restrict__ y, u16* __restrict__ yt) {
  __shared__ u16 tile[64][80];
  const int b = blockIdx.z;
  const int tb = blockIdx.x * 64;
  const int cb = blockIdx.y * 64;
  const int tid = threadIdx.x;
  {
    const int tl = (tid & 7) * 8;
    const int cl = tid >> 3;
    #pragma unroll
    for (int h = 0; h < 2; ++h) {
      const int cc = cl + h * 32;
      const u16x8 v = *(const u16x8*)(y + ((size_t)(b * 512 + cb + cc)) * 2048 + tb + tl);
      #pragma unroll
      for (int i = 0; i < 8; ++i) tile[cc][tl + i] = v[i];
    }
  }
  __syncthreads();
  {
    const int c2 = (tid & 7) * 8;
    const int t2 = tid >> 3;
    #pragma unroll
    for (int h = 0; h < 2; ++h) {
      const int tt = t2 + h * 32;
      u16 tmp[8];
      #pragma unroll
      for (int i = 0; i < 8; ++i) tmp[i] = tile[c2 + i][tt];
      *(u16x8*)(yt + ((size_t)(b * 2048 + tb + tt)) * 512 + cb + c2) = *(u16x8*)tmp;
    }
  }
}

// ---------------- K3: 256x256x(K=512) 8-phase GEMM + GLU ----------------
#define FRAG_A(P, MI, S) __builtin_bit_cast(short8, *(const u16x8*)&lds[       \
    (P) * 16384 + wmh + ((MI) * 16 + lrow) * 64 + ((S) ? cs1 : cs0)])
#define FRAG_B(P, NI, S) __builtin_bit_cast(short8, *(const u16x8*)&lds[       \
    32768 + (P) * 16384 + hBh + (rB + (NI) * 16 + lrow) * 64 + ((S) ? cs1 : cs0)])

#define STAGE_A(KT, H, P) do {                                                 \
    int sr_ = m0 + (H) * 128 + wq8 + l3;                                       \
    int o0_ = (sr_ & 1) ? (512 + (sr_ >> 1)) : (sr_ >> 1);                     \
    gload_lds16(Wb + (size_t)o0_ * 512 + (KT) * 64 + csw,                      \
                lds + (P) * 16384 + (H) * 8192 + wq * 512);                    \
    sr_ += 64;                                                                 \
    int o1_ = (sr_ & 1) ? (512 + (sr_ >> 1)) : (sr_ >> 1);                     \
    gload_lds16(Wb + (size_t)o1_ * 512 + (KT) * 64 + csw,                      \
                lds + (P) * 16384 + (H) * 8192 + 4096 + wq * 512);             \
  } while (0)
#define STAGE_B(KT, H, P) do {                                                 \
    int tr_ = t0b + (H) * 128 + wq8 + l3;                                      \
    gload_lds16(yt + ((size_t)(bb * 2048 + tr_)) * 512 + (KT) * 64 + csw,      \
                lds + 32768 + (P) * 16384 + (H) * 8192 + wq * 512);            \
    gload_lds16(yt + ((size_t)(bb * 2048 + tr_ + 64)) * 512 + (KT) * 64 + csw, \
                lds + 32768 + (P) * 16384 + (H) * 8192 + 4096 + wq * 512);     \
  } while (0)

#define MFMA2(MI, NI, A0, A1)                                                  \
    acc[MI][NI] = __builtin_amdgcn_mfma_f32_16x16x32_bf16(A0, br[NI][0],       \
                                                          acc[MI][NI], 0, 0, 0); \
    acc[MI][NI] = __builtin_amdgcn_mfma_f32_16x16x32_bf16(A1, br[NI][1],       \
                                                          acc[MI][NI], 0, 0, 0);

#define PHASE_CORE(Q, READS, STAGES, VWAIT)                                    \
  {                                                                            \
    short8 a00 = FRAG_A(PP, (Q)*2 + 0, 0), a01 = FRAG_A(PP, (Q)*2 + 0, 1);     \
    short8 a10 = FRAG_A(PP, (Q)*2 + 1, 0), a11 = FRAG_A(PP, (Q)*2 + 1, 1);     \
    READS;                                                                     \
    STAGES;                                                                    \
    __builtin_amdgcn_s_barrier();                                              \
    asm volatile("s_waitcnt lgkmcnt(0)" ::: "memory");                         \
    __builtin_amdgcn_sched_barrier(0);                                         \
    __builtin_amdgcn_s_setprio(1);                                             \
    MFMA2((Q)*2 + 0, 0, a00, a01) MFMA2((Q)*2 + 0, 1, a00, a01)                \
    MFMA2((Q)*2 + 0, 2, a00, a01) MFMA2((Q)*2 + 0, 3, a00, a01)                \
    MFMA2((Q)*2 + 1, 0, a10, a11) MFMA2((Q)*2 + 1, 1, a10, a11)                \
    MFMA2((Q)*2 + 1, 2, a10, a11) MFMA2((Q)*2 + 1, 3, a10, a11)                \
    __builtin_amdgcn_s_setprio(0);                                             \
    __builtin_amdgcn_sched_barrier(0);                                         \
    VWAIT;                                                                     \
    __builtin_amdgcn_s_barrier();                                              \
  }

#define READ_B(P) do {                                                         \
    br[0][0] = FRAG_B(P, 0, 0); br[0][1] = FRAG_B(P, 0, 1);                    \
    br[1][0] = FRAG_B(P, 1, 0); br[1][1] = FRAG_B(P, 1, 1);                    \
    br[2][0] = FRAG_B(P, 2, 0); br[2][1] = FRAG_B(P, 2, 1);                    \
    br[3][0] = FRAG_B(P, 3, 0); br[3][1] = FRAG_B(P, 3, 1);                    \
  } while (0)

__global__ __launch_bounds__(512, 2) void gemm_glu(
    const u16* __restrict__ Wb, const u16* __restrict__ yt,
    const float* __restrict__ bias, float* __restrict__ out) {
  extern __shared__ __align__(16) u16 lds[];
  const int bid = blockIdx.x;
  const int wg = (bid & 7) * 64 + (bid >> 3);  // XCD swizzle (512 = 8*64)
  const int bb = wg >> 5;
  const int mt = (wg >> 3) & 3;
  const int nt = wg & 7;
  const int m0 = mt * 256;
  const int t0b = nt * 256;
  const int tid = threadIdx.x;
  const int lane = tid & 63;
  const int wq = tid >> 6;
  const int wq8 = wq * 8, l3 = lane >> 3;
  const int wm = wq >> 2, wn = wq & 3;
  const int lrow = lane & 15, lq = lane >> 4;
  const int csw = ((lane & 7) ^ l3) * 8;
  const int cs0 = ((lq ^ (lane & 7)) << 3);
  const int cs1 = (((4 + lq) ^ (lane & 7)) << 3);
  const int wmh = wm * 8192;
  const int hBh = (wn >> 1) * 8192;
  const int rB = (wn & 1) * 64;

  f32x4 acc[8][4];
  const f32x4 z4 = {0.f, 0.f, 0.f, 0.f};
  #pragma unroll
  for (int mi = 0; mi < 8; ++mi)
    #pragma unroll
    for (int ni = 0; ni < 4; ++ni) acc[mi][ni] = z4;
  short8 br[4][2];

  STAGE_A(0, 0, 0); STAGE_A(0, 1, 0);
  STAGE_B(0, 0, 0); STAGE_B(0, 1, 0);
  STAGE_B(1, 0, 1); STAGE_B(1, 1, 1);
  asm volatile("s_waitcnt vmcnt(4)" ::: "memory");
  __builtin_amdgcn_s_barrier();

  #pragma unroll
  for (int j = 0; j < 4; ++j) {
    const int e2 = 2 * j + 2, o1 = 2 * j + 1, o3 = 2 * j + 3;
    #define PP 0
    PHASE_CORE(0, READ_B(0), STAGE_A(o1, 0, 1), )
    PHASE_CORE(1, , { STAGE_A(o1, 1, 1); if (j < 3) STAGE_B(e2, 0, 0); }, )
    PHASE_CORE(2, , if (j < 3) STAGE_B(e2, 1, 0), )
    PHASE_CORE(3, , ,
               if (j < 3) { asm volatile("s_waitcnt vmcnt(4)" ::: "memory"); }
               else { asm volatile("s_waitcnt vmcnt(0)" ::: "memory"); })
    #undef PP
    #define PP 1
    PHASE_CORE(0, READ_B(1), if (j < 3) STAGE_A(e2, 0, 0), )
    PHASE_CORE(1, , if (j < 3) STAGE_A(e2, 1, 0), )
    PHASE_CORE(2, , if (j < 3) STAGE_B(o3, 0, 1), )
    PHASE_CORE(3, , if (j < 3) STAGE_B(o3, 1, 1),
               if (j < 3) { asm volatile("s_waitcnt vmcnt(4)" ::: "memory"); })
    #undef PP
  }

  #pragma unroll
  for (int mi = 0; mi < 8; ++mi) {
    const int sr0 = m0 + wm * 128 + mi * 16 + lq * 4;
    const int ch = sr0 >> 1;
    const float ba0 = bias[ch],     bg0 = bias[512 + ch];
    const float ba1 = bias[ch + 1], bg1 = bias[512 + ch + 1];
    #pragma unroll
    for (int ni = 0; ni < 4; ++ni) {
      const int t = t0b + wn * 64 + ni * 16 + (lane & 15);
      const f32x4 v = acc[mi][ni];
      const float a0 = v[0] + ba0, g0 = v[1] + bg0;
      const float a1 = v[2] + ba1, g1 = v[3] + bg1;
      out[((size_t)(bb * 512 + ch)) * 2048 + t]     = a0 * RCP(1.f + __expf(-g0));
      out[((size_t)(bb * 512 + ch + 1)) * 2048 + t] = a1 * RCP(1.f + __expf(-g1));
    }
  }
}

extern "C" void kernel_launch(void* const* d_in, const int* in_sizes, int n_in,
                              void* d_out, int out_size, void* d_ws, size_t ws_size,
                              hipStream_t stream) {
  (void)in_sizes; (void)n_in; (void)out_size; (void)ws_size;
  const float* u      = (const float*)d_in[0];
  const float* log_dt = (const float*)d_in[1];
  const float* Hr     = (const float*)d_in[2];
  const float* Hi     = (const float*)d_in[3];
  const float* Dv     = (const float*)d_in[4];
  const float* W      = (const float*)d_in[5];
  const float* bias   = (const float*)d_in[6];

  char* ws = (char*)d_ws;
  float2* kep = (float2*)(ws);                     // 512*513*4*8 = 8.4 MB
  u16*    Wb  = (u16*)  (ws + ((size_t)9 << 20));  // 1 MB
  u16*    yt  = (u16*)  (ws + ((size_t)12 << 20)); // 32 MB
  u16*    ybf = (u16*)d_out;                       // bf16 y staged in d_out[0,32MB)

  build_kep<<<dim3(512), 512, 0, stream>>>(log_dt, Hr, Hi, Dv, W, kep, Wb);
  fft_conv<<<dim3(2, 512), 512, 0, stream>>>(u, kep, ybf);
  transpose_y<<<dim3(32, 8, 16), 256, 0, stream>>>(ybf, yt);
  gemm_glu<<<dim3(512), 512, 131072, stream>>>(Wb, yt, bias, (float*)d_out);
}

// Round 14
// 127.236 us; speedup vs baseline: 1.0148x; 1.0148x over previous
//
#include <hip/hip_runtime.h>
#include <math.h>

typedef unsigned short u16;
typedef unsigned int u32;
typedef __attribute__((ext_vector_type(8))) short short8;
typedef __attribute__((ext_vector_type(8))) u16 u16x8;
typedef __attribute__((ext_vector_type(4))) float f32x4;

#define PH(i) ((i) + ((i) >> 4))

#if __has_builtin(__builtin_amdgcn_rcpf)
#define RCP(x) __builtin_amdgcn_rcpf(x)
#else
#define RCP(x) (1.0f / (x))
#endif

// LDS-only barrier: drain lgkmcnt (our ds_writes), barrier, pin scheduling.
// Leaves global loads (vmcnt) in flight across the barrier (T4 idiom).
#define LBAR()                                                                 \
  do {                                                                         \
    asm volatile("s_waitcnt lgkmcnt(0)" ::: "memory");                         \
    __builtin_amdgcn_s_barrier();                                              \
    __builtin_amdgcn_sched_barrier(0);                                         \
  } while (0)

static __device__ __forceinline__ u16 f2bf(float x) {
  unsigned u = __builtin_bit_cast(unsigned, x);
  return (u16)((u + 0x7FFFu + ((u >> 16) & 1u)) >> 16);
}

static __device__ __forceinline__ float2 cmul(float2 a, float2 b) {
  return make_float2(a.x * b.x - a.y * b.y, a.x * b.y + a.y * b.x);
}
static __device__ __forceinline__ float2 cadd(float2 a, float2 b) {
  return make_float2(a.x + b.x, a.y + b.y);
}
static __device__ __forceinline__ float2 conjf2(float2 a) {
  return make_float2(a.x, -a.y);
}
static __device__ __forceinline__ float2 mkC(float a, float b) {
  return make_float2(a, b);
}

// tanh-form GELU: y * sigmoid(1.59577*(y + 0.044715 y^3)); max dev ~1e-3
static __device__ __forceinline__ float gelu_fast(float y) {
  const float t = __builtin_fmaf(0.044715f * y * y, y, y);
  const float e = __expf(-1.5957691216f * t);
  return y * RCP(1.f + e);
}

static __device__ __forceinline__ u32 pack_out(float2 r) {
  const u32 lo = f2bf(gelu_fast(r.x));
  const u32 hi = f2bf(gelu_fast(-r.y));
  return lo | (hi << 16);
}

// async global->LDS, 16B per lane
static __device__ __forceinline__ void gload_lds16(const void* g, void* l) {
  __builtin_amdgcn_global_load_lds(
      (const __attribute__((address_space(1))) u32*)g,
      (__attribute__((address_space(3))) u32*)l, 16, 0, 0);
}

#define BF4(A, B, C, D, Y0, Y1, Y2, Y3)                                        \
  {                                                                            \
    const float apcr = (A).x + (C).x, apci = (A).y + (C).y;                    \
    const float amcr = (A).x - (C).x, amci = (A).y - (C).y;                    \
    const float bpdr = (B).x + (D).x, bpdi = (B).y + (D).y;                    \
    const float bmdr = (B).x - (D).x, bmdi = (B).y - (D).y;                    \
    Y0 = make_float2(apcr + bpdr, apci + bpdi);                                \
    Y2 = make_float2(apcr - bpdr, apci - bpdi);                                \
    Y1 = make_float2(amcr + bmdi, amci - bmdr);                                \
    Y3 = make_float2(amcr - bmdi, amci + bmdr);                                \
  }

// ---------------- K1: merged hope-kernel + filter coeffs (+D folded) + W->bf16
static __device__ __forceinline__ void hope_sum(
    const float* __restrict__ log_dt, const float* __restrict__ Hr,
    const float* __restrict__ Hi, int h, int l, float* outr, float* outi) {
  const float dt = expf(log_dt[h]);
  const float phi = 6.28318530717958647692f * (float)l * (1.0f / 1024.0f);
  float sphi, cphi;
  sincosf(phi, &sphi, &cphi);
  const float nr = (1.f + dt) * cphi + dt - 1.f;
  const float ni = (1.f + dt) * sphi;
  const float dr = (dt - 1.f) * cphi + dt + 1.f;
  const float di = (dt - 1.f) * sphi;
  const float theta = atan2f(ni * dr - nr * di, nr * dr + ni * di);
  float sw, cw;
  sincosf(theta, &sw, &cw);
  const float wr = cw, wi = -sw;  // e^{-i theta}
  float cr = wr, ci = wi;
  float ar = 0.f, ai = 0.f;
  const float* __restrict__ hr = Hr + h * 64;
  const float* __restrict__ hi = Hi + h * 64;
  for (int n = 0; n < 64; ++n) {
    const float a = hr[n], bb = hi[n];
    ar += a * cr - bb * ci;
    ai += a * ci + bb * cr;
    const float t = cr * wr - ci * wi;
    ci = cr * wi + ci * wr;
    cr = t;
  }
  *outr = ar;
  *outi = ai;
}

__global__ __launch_bounds__(512) void build_kep(
    const float* __restrict__ log_dt, const float* __restrict__ Hr,
    const float* __restrict__ Hi, const float* __restrict__ Dv,
    const float* __restrict__ W, float2* __restrict__ kep,
    u16* __restrict__ Wb) {
  __shared__ float2 K1[1024], K2[1024];
  const int c = blockIdx.x;
  const int t = threadIdx.x;
  // fold conv_w in: block c converts W[c*1024 .. c*1024+1024)
  Wb[c * 1024 + t] = f2bf(W[c * 1024 + t]);
  Wb[c * 1024 + 512 + t] = f2bf(W[c * 1024 + 512 + t]);
  float r, i;
  hope_sum(log_dt, Hr, Hi, c, t, &r, &i);             K1[t] = make_float2(r, i);
  hope_sum(log_dt, Hr, Hi, c, t + 512, &r, &i);       K1[t + 512] = make_float2(r, i);
  hope_sum(log_dt, Hr, Hi, c + 512, t, &r, &i);       K2[t] = make_float2(r, i);
  hope_sum(log_dt, Hr, Hi, c + 512, t + 512, &r, &i); K2[t + 512] = make_float2(r, i);
  __syncthreads();
  const float s = 1.0f / 2048.0f;   // fold ifft scale (exact)
  const float dcs = Dv[c] * s;      // fold D-skip: k'[f] = k[f] + D[c]
  for (int q = t; q <= 512; q += 512) {  // t==0 also covers q=512
    float2 kf, kg;
    {
      const int qa = q;
      kf = (qa == 0) ? make_float2(K1[0].x * s, 0.f)
                     : make_float2(0.5f * s * (K1[qa].x + K2[qa - 1].x),
                                   0.5f * s * (K1[qa].y - K2[qa - 1].y));
      const int qb = 1024 - q;
      kg = (qb == 1024) ? make_float2(K2[1023].x * s, 0.f)
           : (qb == 0)  ? make_float2(K1[0].x * s, 0.f)
                        : make_float2(0.5f * s * (K1[qb].x + K2[qb - 1].x),
                                      0.5f * s * (K1[qb].y - K2[qb - 1].y));
    }
    kf.x += dcs;
    kg.x += dcs;
    float2 C1, C2, C3, C4;
    if (q == 0) {
      C1 = make_float2(kf.x + kg.x, kg.y - kf.y);
      C2 = make_float2(-(kg.y + kf.y), kg.x - kf.x);
      C3 = C2;
      C4 = C1;
    } else {
      float st, ct;
      sincosf(3.14159265358979323846f * (float)q * (1.f / 1024.f), &st, &ct);
      const float2 A1 = make_float2(1.f - st, -ct);
      const float2 A2 = make_float2(1.f + st, ct);
      const float2 kgc = make_float2(kg.x, -kg.y);
      const float2 t1 = cmul(kf, A1), t2 = cmul(kgc, A2);
      const float2 t3 = cmul(kf, A2), t4 = cmul(kgc, A1);
      const float2 p1 = make_float2(0.5f * (t1.x + t2.x), 0.5f * (t1.y + t2.y));
      const float2 p2 = make_float2(0.5f * (t3.x + t4.x), 0.5f * (t3.y + t4.y));
      const float2 q1 = make_float2(0.5f * (t1.x - t2.x), 0.5f * (t1.y - t2.y));
      const float2 q2 = make_float2(0.5f * (t3.x - t4.x), 0.5f * (t3.y - t4.y));
      const float2 iWc = make_float2(-st, ct);
      const float2 r1 = cmul(iWc, q1), r2 = cmul(iWc, q2);
      C1 = make_float2(p1.x + r1.x, -(p1.y + r1.y));
      C2 = make_float2(p2.x + r2.x, -(p2.y + r2.y));
      C3 = make_float2(p1.x - r1.x, p1.y - r1.y);
      C4 = make_float2(p2.x - r2.x, p2.y - r2.y);
    }
    float2* o = kep + ((size_t)c * 513 + q) * 4;
    o[0] = C1; o[1] = C2; o[2] = C3; o[3] = C4;
  }
}

// ------- K2: Stockham rfft-conv, 2 rows/thread, reg edges, fused filter+s0 ----
static __device__ __forceinline__ void stage_pair(
    const float2* __restrict__ S0, const float2* __restrict__ S1,
    float2* __restrict__ D0, float2* __restrict__ D1,
    int t, int sh, const float2* __restrict__ twl) {
  const int m = 1 << sh;
  const int kk = t & (m - 1);
  const int o = kk + ((t >> sh) << (sh + 2));
  const float2 a0 = S0[PH(t)],       a1 = S1[PH(t)];
  const float2 b0 = S0[PH(t + 256)], b1 = S1[PH(t + 256)];
  const float2 c0 = S0[PH(t + 512)], c1 = S1[PH(t + 512)];
  const float2 d0 = S0[PH(t + 768)], d1 = S1[PH(t + 768)];
  float2 x0, x1, x2, x3, z0, z1, z2, z3;
  BF4(a0, b0, c0, d0, x0, x1, x2, x3);
  BF4(a1, b1, c1, d1, z0, z1, z2, z3);
  const float2 w1 = twl[t - kk];
  const float2 w2 = cmul(w1, w1);
  const float2 w3 = cmul(w2, w1);
  D0[PH(o)] = x0;                   D1[PH(o)] = z0;
  D0[PH(o + m)] = cmul(w1, x1);     D1[PH(o + m)] = cmul(w1, z1);
  D0[PH(o + 2 * m)] = cmul(w2, x2); D1[PH(o + 2 * m)] = cmul(w2, z2);
  D0[PH(o + 3 * m)] = cmul(w3, x3); D1[PH(o + 3 * m)] = cmul(w3, z3);
}

// Last stage (sh=8): twiddle-free, writes LDS (FFT#1 result Z, natural order).
static __device__ __forceinline__ void stage_pair_last(
    const float2* __restrict__ S0, const float2* __restrict__ S1,
    float2* __restrict__ D0, float2* __restrict__ D1, int t) {
  const float2 a0 = S0[PH(t)],       a1 = S1[PH(t)];
  const float2 b0 = S0[PH(t + 256)], b1 = S1[PH(t + 256)];
  const float2 c0 = S0[PH(t + 512)], c1 = S1[PH(t + 512)];
  const float2 d0 = S0[PH(t + 768)], d1 = S1[PH(t + 768)];
  float2 x0, x1, x2, x3, z0, z1, z2, z3;
  BF4(a0, b0, c0, d0, x0, x1, x2, x3);
  BF4(a1, b1, c1, d1, z0, z1, z2, z3);
  D0[PH(t)] = x0;       D1[PH(t)] = z0;
  D0[PH(t + 256)] = x1; D1[PH(t + 256)] = z1;
  D0[PH(t + 512)] = x2; D1[PH(t + 512)] = z2;
  D0[PH(t + 768)] = x3; D1[PH(t + 768)] = z3;
}

__global__ __launch_bounds__(256) void fft_conv(
    const float* __restrict__ u, const float2* __restrict__ kep,
    u16* __restrict__ y) {
  __shared__ float2 bufA[2176], bufB[2176];  // 2 rows x 1088
  __shared__ float2 twl[256];
  const int bq = blockIdx.x, c = blockIdx.y;
  const int t = threadIdx.x;
  {
    float s, cc;
    __sincosf(6.28318530717958647692f * (float)t * (1.f / 1024.f), &s, &cc);
    twl[t] = make_float2(cc, -s);
    // twl reads are always within the writer's own 64-aligned wave group.
  }
  // prefetch filter coefficients; with LDS-only barriers these stay in
  // flight (vmcnt) across all FFT#1 stages and land at the fused filter.
  const float4* __restrict__ krow4 = (const float4*)(kep + (size_t)c * (513 * 4));
  const float4 cA0 = krow4[2 * t];               // C1C2(q=t)
  const float4 cA1 = krow4[2 * (t + 256)];       // C1C2(q=t+256)
  const float4 cC  = krow4[2 * (512 - t) + 1];   // C3C4(q=512-t)
  const float4 cDq = krow4[2 * (256 - t) + 1];   // C3C4(q=256-t)
  const float4 cM  = krow4[1024];                // C1C2(q=512), used iff t==0

  const int b0 = bq * 2, b1 = bq * 2 + 1;
  const float2* __restrict__ u20 = (const float2*)(u + ((size_t)(b0 * 512 + c)) * 2048);
  const float2* __restrict__ u21 = (const float2*)(u + ((size_t)(b1 * 512 + c)) * 2048);
  u32* __restrict__ yr0 = (u32*)(y + ((size_t)(b0 * 512 + c)) * 2048);
  u32* __restrict__ yr1 = (u32*)(y + ((size_t)(b1 * 512 + c)) * 2048);
  float2* A0 = bufA;        float2* A1 = bufA + 1088;
  float2* B0 = bufB;        float2* B1 = bufB + 1088;

  // ---- FFT #1, stage 0 (sh=0) from registers: z[p]=u[2p]+i*u[2p+1] ----
  {
    float2 v0[4], v1[4];
    #pragma unroll
    for (int q = 0; q < 4; ++q) {
      v0[q] = u20[t + 256 * q];
      v1[q] = u21[t + 256 * q];
    }
    float2 x0, x1, x2, x3, z0, z1, z2, z3;
    BF4(v0[0], v0[1], v0[2], v0[3], x0, x1, x2, x3);
    BF4(v1[0], v1[1], v1[2], v1[3], z0, z1, z2, z3);
    const float2 w1 = twl[t];
    const float2 w2 = cmul(w1, w1);
    const float2 w3 = cmul(w2, w1);
    const int o = 4 * t;
    A0[PH(o)] = x0;               A1[PH(o)] = z0;
    A0[PH(o + 1)] = cmul(w1, x1); A1[PH(o + 1)] = cmul(w1, z1);
    A0[PH(o + 2)] = cmul(w2, x2); A1[PH(o + 2)] = cmul(w2, z2);
    A0[PH(o + 3)] = cmul(w3, x3); A1[PH(o + 3)] = cmul(w3, z3);
  }
  LBAR();
  stage_pair(A0, A1, B0, B1, t, 2, twl); LBAR();
  stage_pair(B0, B1, A0, A1, t, 4, twl); LBAR();
  stage_pair(A0, A1, B0, B1, t, 6, twl); LBAR();
  stage_pair_last(B0, B1, A0, A1, t);    LBAR();  // Z in A

  // ---- fused filter + FFT#2 stage 0 (A -> B, conj trick) ----
  {
    const int gp0 = (1024 - t) & 1023;
    const float2 w1 = twl[t];
    const float2 w2 = cmul(w1, w1);
    const float2 w3 = cmul(w2, w1);
    const int o = 4 * t;
    #define FUSED_ROW(Ab, Bb)                                                  \
    {                                                                          \
      const float2 Zf0 = Ab[PH(t)],       Zg0 = Ab[PH(gp0)];                   \
      const float2 Zf1 = Ab[PH(t + 256)], Zg1 = Ab[PH(768 - t)];               \
      const float2 Zc  = Ab[PH(t + 512)], Zcf = Ab[PH(512 - t)];               \
      const float2 Zd  = Ab[PH(t + 768)], Zdf = Ab[PH(256 - t)];               \
      const float2 Da = cadd(cmul(mkC(cA0.x, cA0.y), conjf2(Zf0)),             \
                             cmul(mkC(cA0.z, cA0.w), Zg0));                    \
      const float2 Db = cadd(cmul(mkC(cA1.x, cA1.y), conjf2(Zf1)),             \
                             cmul(mkC(cA1.z, cA1.w), Zg1));                    \
      float2 Dc;                                                               \
      if (t == 0)                                                              \
        Dc = cadd(cmul(mkC(cM.x, cM.y), conjf2(Zc)), cmul(mkC(cM.z, cM.w), Zc)); \
      else                                                                     \
        Dc = cadd(cmul(mkC(cC.x, cC.y), Zcf), cmul(mkC(cC.z, cC.w), conjf2(Zc))); \
      const float2 Dd = cadd(cmul(mkC(cDq.x, cDq.y), Zdf),                     \
                             cmul(mkC(cDq.z, cDq.w), conjf2(Zd)));             \
      float2 x0, x1, x2, x3;                                                   \
      BF4(Da, Db, Dc, Dd, x0, x1, x2, x3);                                     \
      Bb[PH(o)] = x0;                                                          \
      Bb[PH(o + 1)] = cmul(w1, x1);                                            \
      Bb[PH(o + 2)] = cmul(w2, x2);                                            \
      Bb[PH(o + 3)] = cmul(w3, x3);                                            \
    }
    FUSED_ROW(A0, B0)
    FUSED_ROW(A1, B1)
    #undef FUSED_ROW
  }
  LBAR();

  // ---- FFT #2 remaining stages, last stage to registers ----
  stage_pair(B0, B1, A0, A1, t, 2, twl); LBAR();
  stage_pair(A0, A1, B0, B1, t, 4, twl); LBAR();
  stage_pair(B0, B1, A0, A1, t, 6, twl); LBAR();
  {
    const float2 pa0 = A0[PH(t)],       pa1 = A1[PH(t)];
    const float2 pb0 = A0[PH(t + 256)], pb1 = A1[PH(t + 256)];
    const float2 pc0 = A0[PH(t + 512)], pc1 = A1[PH(t + 512)];
    const float2 pd0 = A0[PH(t + 768)], pd1 = A1[PH(t + 768)];
    float2 x0, x1, x2, x3, z0, z1, z2, z3;
    BF4(pa0, pb0, pc0, pd0, x0, x1, x2, x3);
    BF4(pa1, pb1, pc1, pd1, z0, z1, z2, z3);
    // point p = t + 256r -> output word p (2 bf16); D-skip folded into kep
    yr0[t] = pack_out(x0);       yr1[t] = pack_out(z0);
    yr0[t + 256] = pack_out(x1); yr1[t + 256] = pack_out(z1);
    yr0[t + 512] = pack_out(x2); yr1[t + 512] = pack_out(z2);
    yr0[t + 768] = pack_out(x3); yr1[t + 768] = pack_out(z3);
  }
}

// ---------------- K2b: y (B,C,L) bf16 -> yt (B,L,C) bf16 ----------------
__global__ __launch_bounds__(256) void transpose_y(
    const u16* __restrict__ y, u16* __restrict__ yt) {
  __shared__ u16 tile[64][80];
  const int b = blockIdx.z;
  const int tb = blockIdx.x * 64;
  const int cb = blockIdx.y * 64;
  const int tid = threadIdx.x;
  {
    const int tl = (tid & 7) * 8;
    const int cl = tid >> 3;
    #pragma unroll
    for (int h = 0; h < 2; ++h) {
      const int cc = cl + h * 32;
      const u16x8 v = *(const u16x8*)(y + ((size_t)(b * 512 + cb + cc)) * 2048 + tb + tl);
      #pragma unroll
      for (int i = 0; i < 8; ++i) tile[cc][tl + i] = v[i];
    }
  }
  __syncthreads();
  {
    const int c2 = (tid & 7) * 8;
    const int t2 = tid >> 3;
    #pragma unroll
    for (int h = 0; h < 2; ++h) {
      const int tt = t2 + h * 32;
      u16 tmp[8];
      #pragma unroll
      for (int i = 0; i < 8; ++i) tmp[i] = tile[c2 + i][tt];
      *(u16x8*)(yt + ((size_t)(b * 2048 + tb + tt)) * 512 + cb + c2) = *(u16x8*)tmp;
    }
  }
}

// ---------------- K3: 256x256x(K=512) 8-phase GEMM + GLU ----------------
#define FRAG_A(P, MI, S) __builtin_bit_cast(short8, *(const u16x8*)&lds[       \
    (P) * 16384 + wmh + ((MI) * 16 + lrow) * 64 + ((S) ? cs1 : cs0)])
#define FRAG_B(P, NI, S) __builtin_bit_cast(short8, *(const u16x8*)&lds[       \
    32768 + (P) * 16384 + hBh + (rB + (NI) * 16 + lrow) * 64 + ((S) ? cs1 : cs0)])

#define STAGE_A(KT, H, P) do {                                                 \
    int sr_ = m0 + (H) * 128 + wq8 + l3;                                       \
    int o0_ = (sr_ & 1) ? (512 + (sr_ >> 1)) : (sr_ >> 1);                     \
    gload_lds16(Wb + (size_t)o0_ * 512 + (KT) * 64 + csw,                      \
                lds + (P) * 16384 + (H) * 8192 + wq * 512);                    \
    sr_ += 64;                                                                 \
    int o1_ = (sr_ & 1) ? (512 + (sr_ >> 1)) : (sr_ >> 1);                     \
    gload_lds16(Wb + (size_t)o1_ * 512 + (KT) * 64 + csw,                      \
                lds + (P) * 16384 + (H) * 8192 + 4096 + wq * 512);             \
  } while (0)
#define STAGE_B(KT, H, P) do {                                                 \
    int tr_ = t0b + (H) * 128 + wq8 + l3;                                      \
    gload_lds16(yt + ((size_t)(bb * 2048 + tr_)) * 512 + (KT) * 64 + csw,      \
                lds + 32768 + (P) * 16384 + (H) * 8192 + wq * 512);            \
    gload_lds16(yt + ((size_t)(bb * 2048 + tr_ + 64)) * 512 + (KT) * 64 + csw, \
                lds + 32768 + (P) * 16384 + (H) * 8192 + 4096 + wq * 512);     \
  } while (0)

#define MFMA2(MI, NI, A0, A1)                                                  \
    acc[MI][NI] = __builtin_amdgcn_mfma_f32_16x16x32_bf16(A0, br[NI][0],       \
                                                          acc[MI][NI], 0, 0, 0); \
    acc[MI][NI] = __builtin_amdgcn_mfma_f32_16x16x32_bf16(A1, br[NI][1],       \
                                                          acc[MI][NI], 0, 0, 0);

#define PHASE_CORE(Q, READS, STAGES, VWAIT)                                    \
  {                                                                            \
    short8 a00 = FRAG_A(PP, (Q)*2 + 0, 0), a01 = FRAG_A(PP, (Q)*2 + 0, 1);     \
    short8 a10 = FRAG_A(PP, (Q)*2 + 1, 0), a11 = FRAG_A(PP, (Q)*2 + 1, 1);     \
    READS;                                                                     \
    STAGES;                                                                    \
    __builtin_amdgcn_s_barrier();                                              \
    asm volatile("s_waitcnt lgkmcnt(0)" ::: "memory");                         \
    __builtin_amdgcn_sched_barrier(0);                                         \
    __builtin_amdgcn_s_setprio(1);                                             \
    MFMA2((Q)*2 + 0, 0, a00, a01) MFMA2((Q)*2 + 0, 1, a00, a01)                \
    MFMA2((Q)*2 + 0, 2, a00, a01) MFMA2((Q)*2 + 0, 3, a00, a01)                \
    MFMA2((Q)*2 + 1, 0, a10, a11) MFMA2((Q)*2 + 1, 1, a10, a11)                \
    MFMA2((Q)*2 + 1, 2, a10, a11) MFMA2((Q)*2 + 1, 3, a10, a11)                \
    __builtin_amdgcn_s_setprio(0);                                             \
    __builtin_amdgcn_sched_barrier(0);                                         \
    VWAIT;                                                                     \
    __builtin_amdgcn_s_barrier();                                              \
  }

#define READ_B(P) do {                                                         \
    br[0][0] = FRAG_B(P, 0, 0); br[0][1] = FRAG_B(P, 0, 1);                    \
    br[1][0] = FRAG_B(P, 1, 0); br[1][1] = FRAG_B(P, 1, 1);                    \
    br[2][0] = FRAG_B(P, 2, 0); br[2][1] = FRAG_B(P, 2, 1);                    \
    br[3][0] = FRAG_B(P, 3, 0); br[3][1] = FRAG_B(P, 3, 1);                    \
  } while (0)

__global__ __launch_bounds__(512, 2) void gemm_glu(
    const u16* __restrict__ Wb, const u16* __restrict__ yt,
    const float* __restrict__ bias, float* __restrict__ out) {
  extern __shared__ __align__(16) u16 lds[];
  const int bid = blockIdx.x;
  const int wg = (bid & 7) * 64 + (bid >> 3);  // XCD swizzle (512 = 8*64)
  const int bb = wg >> 5;
  const int mt = (wg >> 3) & 3;
  const int nt = wg & 7;
  const int m0 = mt * 256;
  const int t0b = nt * 256;
  const int tid = threadIdx.x;
  const int lane = tid & 63;
  const int wq = tid >> 6;
  const int wq8 = wq * 8, l3 = lane >> 3;
  const int wm = wq >> 2, wn = wq & 3;
  const int lrow = lane & 15, lq = lane >> 4;
  const int csw = ((lane & 7) ^ l3) * 8;
  const int cs0 = ((lq ^ (lane & 7)) << 3);
  const int cs1 = (((4 + lq) ^ (lane & 7)) << 3);
  const int wmh = wm * 8192;
  const int hBh = (wn >> 1) * 8192;
  const int rB = (wn & 1) * 64;

  f32x4 acc[8][4];
  const f32x4 z4 = {0.f, 0.f, 0.f, 0.f};
  #pragma unroll
  for (int mi = 0; mi < 8; ++mi)
    #pragma unroll
    for (int ni = 0; ni < 4; ++ni) acc[mi][ni] = z4;
  short8 br[4][2];

  STAGE_A(0, 0, 0); STAGE_A(0, 1, 0);
  STAGE_B(0, 0, 0); STAGE_B(0, 1, 0);
  STAGE_B(1, 0, 1); STAGE_B(1, 1, 1);
  asm volatile("s_waitcnt vmcnt(4)" ::: "memory");
  __builtin_amdgcn_s_barrier();

  #pragma unroll
  for (int j = 0; j < 4; ++j) {
    const int e2 = 2 * j + 2, o1 = 2 * j + 1, o3 = 2 * j + 3;
    #define PP 0
    PHASE_CORE(0, READ_B(0), STAGE_A(o1, 0, 1), )
    PHASE_CORE(1, , { STAGE_A(o1, 1, 1); if (j < 3) STAGE_B(e2, 0, 0); }, )
    PHASE_CORE(2, , if (j < 3) STAGE_B(e2, 1, 0), )
    PHASE_CORE(3, , ,
               if (j < 3) { asm volatile("s_waitcnt vmcnt(4)" ::: "memory"); }
               else { asm volatile("s_waitcnt vmcnt(0)" ::: "memory"); })
    #undef PP
    #define PP 1
    PHASE_CORE(0, READ_B(1), if (j < 3) STAGE_A(e2, 0, 0), )
    PHASE_CORE(1, , if (j < 3) STAGE_A(e2, 1, 0), )
    PHASE_CORE(2, , if (j < 3) STAGE_B(o3, 0, 1), )
    PHASE_CORE(3, , if (j < 3) STAGE_B(o3, 1, 1),
               if (j < 3) { asm volatile("s_waitcnt vmcnt(4)" ::: "memory"); })
    #undef PP
  }

  #pragma unroll
  for (int mi = 0; mi < 8; ++mi) {
    const int sr0 = m0 + wm * 128 + mi * 16 + lq * 4;
    const int ch = sr0 >> 1;
    const float ba0 = bias[ch],     bg0 = bias[512 + ch];
    const float ba1 = bias[ch + 1], bg1 = bias[512 + ch + 1];
    #pragma unroll
    for (int ni = 0; ni < 4; ++ni) {
      const int t = t0b + wn * 64 + ni * 16 + (lane & 15);
      const f32x4 v = acc[mi][ni];
      const float a0 = v[0] + ba0, g0 = v[1] + bg0;
      const float a1 = v[2] + ba1, g1 = v[3] + bg1;
      out[((size_t)(bb * 512 + ch)) * 2048 + t]     = a0 * RCP(1.f + __expf(-g0));
      out[((size_t)(bb * 512 + ch + 1)) * 2048 + t] = a1 * RCP(1.f + __expf(-g1));
    }
  }
}

extern "C" void kernel_launch(void* const* d_in, const int* in_sizes, int n_in,
                              void* d_out, int out_size, void* d_ws, size_t ws_size,
                              hipStream_t stream) {
  (void)in_sizes; (void)n_in; (void)out_size; (void)ws_size;
  const float* u      = (const float*)d_in[0];
  const float* log_dt = (const float*)d_in[1];
  const float* Hr     = (const float*)d_in[2];
  const float* Hi     = (const float*)d_in[3];
  const float* Dv     = (const float*)d_in[4];
  const float* W      = (const float*)d_in[5];
  const float* bias   = (const float*)d_in[6];

  char* ws = (char*)d_ws;
  float2* kep = (float2*)(ws);                     // 512*513*4*8 = 8.4 MB
  u16*    Wb  = (u16*)  (ws + ((size_t)9 << 20));  // 1 MB
  u16*    yt  = (u16*)  (ws + ((size_t)12 << 20)); // 32 MB
  u16*    ybf = (u16*)d_out;                       // bf16 y staged in d_out[0,32MB)

  build_kep<<<dim3(512), 512, 0, stream>>>(log_dt, Hr, Hi, Dv, W, kep, Wb);
  fft_conv<<<dim3(8, 512), 256, 0, stream>>>(u, kep, ybf);
  transpose_y<<<dim3(32, 8, 16), 256, 0, stream>>>(ybf, yt);
  gemm_glu<<<dim3(512), 512, 131072, stream>>>(Wb, yt, bias, (float*)d_out);
}

// Round 15
// 125.134 us; speedup vs baseline: 1.0319x; 1.0168x over previous
//
#include <hip/hip_runtime.h>
#include <math.h>

typedef unsigned short u16;
typedef unsigned int u32;
typedef __attribute__((ext_vector_type(8))) short short8;
typedef __attribute__((ext_vector_type(8))) u16 u16x8;
typedef __attribute__((ext_vector_type(4))) float f32x4;

// XOR swizzle: bijective within 1024, spreads 16-stride clusters across all
// 16 bank-pairs (verified per-stage: reads stride-256, writes sh=0/2/4/6,
// filter gathers). Zero size overhead -> 4 x 8KB buffers = 32768 B exactly.
#define SW(i) ((i) ^ (((i) >> 4) & 15))

#if __has_builtin(__builtin_amdgcn_rcpf)
#define RCP(x) __builtin_amdgcn_rcpf(x)
#else
#define RCP(x) (1.0f / (x))
#endif

// LDS-only barrier (T4): drain lgkmcnt, barrier, pin scheduling.
#define LBAR()                                                                 \
  do {                                                                         \
    asm volatile("s_waitcnt lgkmcnt(0)" ::: "memory");                         \
    __builtin_amdgcn_s_barrier();                                              \
    __builtin_amdgcn_sched_barrier(0);                                         \
  } while (0)

static __device__ __forceinline__ u16 f2bf(float x) {
  unsigned u = __builtin_bit_cast(unsigned, x);
  return (u16)((u + 0x7FFFu + ((u >> 16) & 1u)) >> 16);
}

static __device__ __forceinline__ float2 cmul(float2 a, float2 b) {
  return make_float2(a.x * b.x - a.y * b.y, a.x * b.y + a.y * b.x);
}
static __device__ __forceinline__ float2 cadd(float2 a, float2 b) {
  return make_float2(a.x + b.x, a.y + b.y);
}
static __device__ __forceinline__ float2 conjf2(float2 a) {
  return make_float2(a.x, -a.y);
}
static __device__ __forceinline__ float2 mkC(float a, float b) {
  return make_float2(a, b);
}

// W_1024^j = e^{-2pi i j/1024}, computed on the fly (frees the LDS table)
static __device__ __forceinline__ float2 twd(int j) {
  float s, c;
  __sincosf((float)j * -0.00613592315154256492f, &s, &c);
  return make_float2(c, s);
}

// tanh-form GELU: y * sigmoid(1.59577*(y + 0.044715 y^3)); max dev ~1e-3
static __device__ __forceinline__ float gelu_fast(float y) {
  const float t = __builtin_fmaf(0.044715f * y * y, y, y);
  const float e = __expf(-1.5957691216f * t);
  return y * RCP(1.f + e);
}

static __device__ __forceinline__ u32 pack_out(float2 r) {
  const u32 lo = f2bf(gelu_fast(r.x));
  const u32 hi = f2bf(gelu_fast(-r.y));
  return lo | (hi << 16);
}

// async global->LDS, 16B per lane
static __device__ __forceinline__ void gload_lds16(const void* g, void* l) {
  __builtin_amdgcn_global_load_lds(
      (const __attribute__((address_space(1))) u32*)g,
      (__attribute__((address_space(3))) u32*)l, 16, 0, 0);
}

#define BF4(A, B, C, D, Y0, Y1, Y2, Y3)                                        \
  {                                                                            \
    const float apcr = (A).x + (C).x, apci = (A).y + (C).y;                    \
    const float amcr = (A).x - (C).x, amci = (A).y - (C).y;                    \
    const float bpdr = (B).x + (D).x, bpdi = (B).y + (D).y;                    \
    const float bmdr = (B).x - (D).x, bmdi = (B).y - (D).y;                    \
    Y0 = make_float2(apcr + bpdr, apci + bpdi);                                \
    Y2 = make_float2(apcr - bpdr, apci - bpdi);                                \
    Y1 = make_float2(amcr + bmdi, amci - bmdr);                                \
    Y3 = make_float2(amcr - bmdi, amci + bmdr);                                \
  }

// ---------------- K1: merged hope-kernel + filter coeffs (+D folded) + W->bf16
static __device__ __forceinline__ void hope_sum(
    const float* __restrict__ log_dt, const float* __restrict__ Hr,
    const float* __restrict__ Hi, int h, int l, float* outr, float* outi) {
  const float dt = expf(log_dt[h]);
  const float phi = 6.28318530717958647692f * (float)l * (1.0f / 1024.0f);
  float sphi, cphi;
  sincosf(phi, &sphi, &cphi);
  const float nr = (1.f + dt) * cphi + dt - 1.f;
  const float ni = (1.f + dt) * sphi;
  const float dr = (dt - 1.f) * cphi + dt + 1.f;
  const float di = (dt - 1.f) * sphi;
  const float theta = atan2f(ni * dr - nr * di, nr * dr + ni * di);
  float sw, cw;
  sincosf(theta, &sw, &cw);
  const float wr = cw, wi = -sw;  // e^{-i theta}
  float cr = wr, ci = wi;
  float ar = 0.f, ai = 0.f;
  const float* __restrict__ hr = Hr + h * 64;
  const float* __restrict__ hi = Hi + h * 64;
  for (int n = 0; n < 64; ++n) {
    const float a = hr[n], bb = hi[n];
    ar += a * cr - bb * ci;
    ai += a * ci + bb * cr;
    const float t = cr * wr - ci * wi;
    ci = cr * wi + ci * wr;
    cr = t;
  }
  *outr = ar;
  *outi = ai;
}

__global__ __launch_bounds__(512) void build_kep(
    const float* __restrict__ log_dt, const float* __restrict__ Hr,
    const float* __restrict__ Hi, const float* __restrict__ Dv,
    const float* __restrict__ W, float2* __restrict__ kep,
    u16* __restrict__ Wb) {
  __shared__ float2 K1[1024], K2[1024];
  const int c = blockIdx.x;
  const int t = threadIdx.x;
  // fold conv_w in: block c converts W[c*1024 .. c*1024+1024)
  Wb[c * 1024 + t] = f2bf(W[c * 1024 + t]);
  Wb[c * 1024 + 512 + t] = f2bf(W[c * 1024 + 512 + t]);
  float r, i;
  hope_sum(log_dt, Hr, Hi, c, t, &r, &i);             K1[t] = make_float2(r, i);
  hope_sum(log_dt, Hr, Hi, c, t + 512, &r, &i);       K1[t + 512] = make_float2(r, i);
  hope_sum(log_dt, Hr, Hi, c + 512, t, &r, &i);       K2[t] = make_float2(r, i);
  hope_sum(log_dt, Hr, Hi, c + 512, t + 512, &r, &i); K2[t + 512] = make_float2(r, i);
  __syncthreads();
  const float s = 1.0f / 2048.0f;   // fold ifft scale (exact)
  const float dcs = Dv[c] * s;      // fold D-skip: k'[f] = k[f] + D[c]
  for (int q = t; q <= 512; q += 512) {  // t==0 also covers q=512
    float2 kf, kg;
    {
      const int qa = q;
      kf = (qa == 0) ? make_float2(K1[0].x * s, 0.f)
                     : make_float2(0.5f * s * (K1[qa].x + K2[qa - 1].x),
                                   0.5f * s * (K1[qa].y - K2[qa - 1].y));
      const int qb = 1024 - q;
      kg = (qb == 1024) ? make_float2(K2[1023].x * s, 0.f)
           : (qb == 0)  ? make_float2(K1[0].x * s, 0.f)
                        : make_float2(0.5f * s * (K1[qb].x + K2[qb - 1].x),
                                      0.5f * s * (K1[qb].y - K2[qb - 1].y));
    }
    kf.x += dcs;
    kg.x += dcs;
    float2 C1, C2, C3, C4;
    if (q == 0) {
      C1 = make_float2(kf.x + kg.x, kg.y - kf.y);
      C2 = make_float2(-(kg.y + kf.y), kg.x - kf.x);
      C3 = C2;
      C4 = C1;
    } else {
      float st, ct;
      sincosf(3.14159265358979323846f * (float)q * (1.f / 1024.f), &st, &ct);
      const float2 A1 = make_float2(1.f - st, -ct);
      const float2 A2 = make_float2(1.f + st, ct);
      const float2 kgc = make_float2(kg.x, -kg.y);
      const float2 t1 = cmul(kf, A1), t2 = cmul(kgc, A2);
      const float2 t3 = cmul(kf, A2), t4 = cmul(kgc, A1);
      const float2 p1 = make_float2(0.5f * (t1.x + t2.x), 0.5f * (t1.y + t2.y));
      const float2 p2 = make_float2(0.5f * (t3.x + t4.x), 0.5f * (t3.y + t4.y));
      const float2 q1 = make_float2(0.5f * (t1.x - t2.x), 0.5f * (t1.y - t2.y));
      const float2 q2 = make_float2(0.5f * (t3.x - t4.x), 0.5f * (t3.y - t4.y));
      const float2 iWc = make_float2(-st, ct);
      const float2 r1 = cmul(iWc, q1), r2 = cmul(iWc, q2);
      C1 = make_float2(p1.x + r1.x, -(p1.y + r1.y));
      C2 = make_float2(p2.x + r2.x, -(p2.y + r2.y));
      C3 = make_float2(p1.x - r1.x, p1.y - r1.y);
      C4 = make_float2(p2.x - r2.x, p2.y - r2.y);
    }
    float2* o = kep + ((size_t)c * 513 + q) * 4;
    o[0] = C1; o[1] = C2; o[2] = C3; o[3] = C4;
  }
}

// ------- K2: Stockham rfft-conv, 2 rows/thread, reg edges, fused filter+s0 ----
// 32 KB LDS exactly (5 blocks/CU); XOR-swizzled layout, computed twiddles.
static __device__ __forceinline__ void stage_pair(
    const float2* __restrict__ S0, const float2* __restrict__ S1,
    float2* __restrict__ D0, float2* __restrict__ D1, int t, int sh) {
  const int m = 1 << sh;
  const int kk = t & (m - 1);
  const int o = kk + ((t >> sh) << (sh + 2));
  const float2 a0 = S0[SW(t)],       a1 = S1[SW(t)];
  const float2 b0 = S0[SW(t + 256)], b1 = S1[SW(t + 256)];
  const float2 c0 = S0[SW(t + 512)], c1 = S1[SW(t + 512)];
  const float2 d0 = S0[SW(t + 768)], d1 = S1[SW(t + 768)];
  float2 x0, x1, x2, x3, z0, z1, z2, z3;
  BF4(a0, b0, c0, d0, x0, x1, x2, x3);
  BF4(a1, b1, c1, d1, z0, z1, z2, z3);
  const float2 w1 = twd((t >> sh) << sh);
  const float2 w2 = cmul(w1, w1);
  const float2 w3 = cmul(w2, w1);
  D0[SW(o)] = x0;                   D1[SW(o)] = z0;
  D0[SW(o + m)] = cmul(w1, x1);     D1[SW(o + m)] = cmul(w1, z1);
  D0[SW(o + 2 * m)] = cmul(w2, x2); D1[SW(o + 2 * m)] = cmul(w2, z2);
  D0[SW(o + 3 * m)] = cmul(w3, x3); D1[SW(o + 3 * m)] = cmul(w3, z3);
}

// Last stage (sh=8): twiddle-free, writes LDS (FFT#1 result Z, natural order).
static __device__ __forceinline__ void stage_pair_last(
    const float2* __restrict__ S0, const float2* __restrict__ S1,
    float2* __restrict__ D0, float2* __restrict__ D1, int t) {
  const float2 a0 = S0[SW(t)],       a1 = S1[SW(t)];
  const float2 b0 = S0[SW(t + 256)], b1 = S1[SW(t + 256)];
  const float2 c0 = S0[SW(t + 512)], c1 = S1[SW(t + 512)];
  const float2 d0 = S0[SW(t + 768)], d1 = S1[SW(t + 768)];
  float2 x0, x1, x2, x3, z0, z1, z2, z3;
  BF4(a0, b0, c0, d0, x0, x1, x2, x3);
  BF4(a1, b1, c1, d1, z0, z1, z2, z3);
  D0[SW(t)] = x0;       D1[SW(t)] = z0;
  D0[SW(t + 256)] = x1; D1[SW(t + 256)] = z1;
  D0[SW(t + 512)] = x2; D1[SW(t + 512)] = z2;
  D0[SW(t + 768)] = x3; D1[SW(t + 768)] = z3;
}

__global__ __launch_bounds__(256) void fft_conv(
    const float* __restrict__ u, const float2* __restrict__ kep,
    u16* __restrict__ y) {
  __shared__ float2 bufA[2048], bufB[2048];  // 32768 B exactly -> 5 blocks/CU
  const int bq = blockIdx.x, c = blockIdx.y;
  const int t = threadIdx.x;

  // prefetch filter coefficients (land at the fused filter; LDS-only barriers
  // keep them in flight across FFT#1 stages).
  const float4* __restrict__ krow4 = (const float4*)(kep + (size_t)c * (513 * 4));
  const float4 cA0 = krow4[2 * t];               // C1C2(q=t)
  const float4 cA1 = krow4[2 * (t + 256)];       // C1C2(q=t+256)
  const float4 cC  = krow4[2 * (512 - t) + 1];   // C3C4(q=512-t)
  const float4 cDq = krow4[2 * (256 - t) + 1];   // C3C4(q=256-t)
  const float4 cM  = krow4[1024];                // C1C2(q=512), used iff t==0

  const int b0 = bq * 2, b1 = bq * 2 + 1;
  const float2* __restrict__ u20 = (const float2*)(u + ((size_t)(b0 * 512 + c)) * 2048);
  const float2* __restrict__ u21 = (const float2*)(u + ((size_t)(b1 * 512 + c)) * 2048);
  u32* __restrict__ yr0 = (u32*)(y + ((size_t)(b0 * 512 + c)) * 2048);
  u32* __restrict__ yr1 = (u32*)(y + ((size_t)(b1 * 512 + c)) * 2048);
  float2* A0 = bufA;        float2* A1 = bufA + 1024;
  float2* B0 = bufB;        float2* B1 = bufB + 1024;

  // ---- FFT #1, stage 0 (sh=0) from registers: z[p]=u[2p]+i*u[2p+1] ----
  {
    float2 v0[4], v1[4];
    #pragma unroll
    for (int q = 0; q < 4; ++q) {
      v0[q] = u20[t + 256 * q];
      v1[q] = u21[t + 256 * q];
    }
    float2 x0, x1, x2, x3, z0, z1, z2, z3;
    BF4(v0[0], v0[1], v0[2], v0[3], x0, x1, x2, x3);
    BF4(v1[0], v1[1], v1[2], v1[3], z0, z1, z2, z3);
    const float2 w1 = twd(t);
    const float2 w2 = cmul(w1, w1);
    const float2 w3 = cmul(w2, w1);
    const int o = 4 * t;
    A0[SW(o)] = x0;               A1[SW(o)] = z0;
    A0[SW(o + 1)] = cmul(w1, x1); A1[SW(o + 1)] = cmul(w1, z1);
    A0[SW(o + 2)] = cmul(w2, x2); A1[SW(o + 2)] = cmul(w2, z2);
    A0[SW(o + 3)] = cmul(w3, x3); A1[SW(o + 3)] = cmul(w3, z3);
  }
  LBAR();
  stage_pair(A0, A1, B0, B1, t, 2); LBAR();
  stage_pair(B0, B1, A0, A1, t, 4); LBAR();
  stage_pair(A0, A1, B0, B1, t, 6); LBAR();
  stage_pair_last(B0, B1, A0, A1, t); LBAR();  // Z in A

  // ---- fused filter + FFT#2 stage 0 (A -> B, conj trick) ----
  {
    const int gp0 = (1024 - t) & 1023;
    const float2 w1 = twd(t);
    const float2 w2 = cmul(w1, w1);
    const float2 w3 = cmul(w2, w1);
    const int o = 4 * t;
    #define FUSED_ROW(Ab, Bb)                                                  \
    {                                                                          \
      const float2 Zf0 = Ab[SW(t)],       Zg0 = Ab[SW(gp0)];                   \
      const float2 Zf1 = Ab[SW(t + 256)], Zg1 = Ab[SW(768 - t)];               \
      const float2 Zc  = Ab[SW(t + 512)], Zcf = Ab[SW(512 - t)];               \
      const float2 Zd  = Ab[SW(t + 768)], Zdf = Ab[SW(256 - t)];               \
      const float2 Da = cadd(cmul(mkC(cA0.x, cA0.y), conjf2(Zf0)),             \
                             cmul(mkC(cA0.z, cA0.w), Zg0));                    \
      const float2 Db = cadd(cmul(mkC(cA1.x, cA1.y), conjf2(Zf1)),             \
                             cmul(mkC(cA1.z, cA1.w), Zg1));                    \
      float2 Dc;                                                               \
      if (t == 0)                                                              \
        Dc = cadd(cmul(mkC(cM.x, cM.y), conjf2(Zc)), cmul(mkC(cM.z, cM.w), Zc)); \
      else                                                                     \
        Dc = cadd(cmul(mkC(cC.x, cC.y), Zcf), cmul(mkC(cC.z, cC.w), conjf2(Zc))); \
      const float2 Dd = cadd(cmul(mkC(cDq.x, cDq.y), Zdf),                     \
                             cmul(mkC(cDq.z, cDq.w), conjf2(Zd)));             \
      float2 x0, x1, x2, x3;                                                   \
      BF4(Da, Db, Dc, Dd, x0, x1, x2, x3);                                     \
      Bb[SW(o)] = x0;                                                          \
      Bb[SW(o + 1)] = cmul(w1, x1);                                            \
      Bb[SW(o + 2)] = cmul(w2, x2);                                            \
      Bb[SW(o + 3)] = cmul(w3, x3);                                            \
    }
    FUSED_ROW(A0, B0)
    FUSED_ROW(A1, B1)
    #undef FUSED_ROW
  }
  LBAR();

  // ---- FFT #2 remaining stages, last stage to registers ----
  stage_pair(B0, B1, A0, A1, t, 2); LBAR();
  stage_pair(A0, A1, B0, B1, t, 4); LBAR();
  stage_pair(B0, B1, A0, A1, t, 6); LBAR();
  {
    const float2 pa0 = A0[SW(t)],       pa1 = A1[SW(t)];
    const float2 pb0 = A0[SW(t + 256)], pb1 = A1[SW(t + 256)];
    const float2 pc0 = A0[SW(t + 512)], pc1 = A1[SW(t + 512)];
    const float2 pd0 = A0[SW(t + 768)], pd1 = A1[SW(t + 768)];
    float2 x0, x1, x2, x3, z0, z1, z2, z3;
    BF4(pa0, pb0, pc0, pd0, x0, x1, x2, x3);
    BF4(pa1, pb1, pc1, pd1, z0, z1, z2, z3);
    // point p = t + 256r -> output word p (2 bf16); D-skip folded into kep
    yr0[t] = pack_out(x0);       yr1[t] = pack_out(z0);
    yr0[t + 256] = pack_out(x1); yr1[t + 256] = pack_out(z1);
    yr0[t + 512] = pack_out(x2); yr1[t + 512] = pack_out(z2);
    yr0[t + 768] = pack_out(x3); yr1[t + 768] = pack_out(z3);
  }
}

// ---------------- K2b: y (B,C,L) bf16 -> yt (B,L,C) bf16 ----------------
__global__ __launch_bounds__(256) void transpose_y(
    const u16* __restrict__ y, u16* __restrict__ yt) {
  __shared__ u16 tile[64][80];
  const int b = blockIdx.z;
  const int tb = blockIdx.x * 64;
  const int cb = blockIdx.y * 64;
  const int tid = threadIdx.x;
  {
    const int tl = (tid & 7) * 8;
    const int cl = tid >> 3;
    #pragma unroll
    for (int h = 0; h < 2; ++h) {
      const int cc = cl + h * 32;
      const u16x8 v = *(const u16x8*)(y + ((size_t)(b * 512 + cb + cc)) * 2048 + tb + tl);
      #pragma unroll
      for (int i = 0; i < 8; ++i) tile[cc][tl + i] = v[i];
    }
  }
  __syncthreads();
  {
    const int c2 = (tid & 7) * 8;
    const int t2 = tid >> 3;
    #pragma unroll
    for (int h = 0; h < 2; ++h) {
      const int tt = t2 + h * 32;
      u16 tmp[8];
      #pragma unroll
      for (int i = 0; i < 8; ++i) tmp[i] = tile[c2 + i][tt];
      *(u16x8*)(yt + ((size_t)(b * 2048 + tb + tt)) * 512 + cb + c2) = *(u16x8*)tmp;
    }
  }
}

// ---------------- K3: 256x256x(K=512) 8-phase GEMM + GLU ----------------
#define FRAG_A(P, MI, S) __builtin_bit_cast(short8, *(const u16x8*)&lds[       \
    (P) * 16384 + wmh + ((MI) * 16 + lrow) * 64 + ((S) ? cs1 : cs0)])
#define FRAG_B(P, NI, S) __builtin_bit_cast(short8, *(const u16x8*)&lds[       \
    32768 + (P) * 16384 + hBh + (rB + (NI) * 16 + lrow) * 64 + ((S) ? cs1 : cs0)])

#define STAGE_A(KT, H, P) do {                                                 \
    int sr_ = m0 + (H) * 128 + wq8 + l3;                                       \
    int o0_ = (sr_ & 1) ? (512 + (sr_ >> 1)) : (sr_ >> 1);                     \
    gload_lds16(Wb + (size_t)o0_ * 512 + (KT) * 64 + csw,                      \
                lds + (P) * 16384 + (H) * 8192 + wq * 512);                    \
    sr_ += 64;                                                                 \
    int o1_ = (sr_ & 1) ? (512 + (sr_ >> 1)) : (sr_ >> 1);                     \
    gload_lds16(Wb + (size_t)o1_ * 512 + (KT) * 64 + csw,                      \
                lds + (P) * 16384 + (H) * 8192 + 4096 + wq * 512);             \
  } while (0)
#define STAGE_B(KT, H, P) do {                                                 \
    int tr_ = t0b + (H) * 128 + wq8 + l3;                                      \
    gload_lds16(yt + ((size_t)(bb * 2048 + tr_)) * 512 + (KT) * 64 + csw,      \
                lds + 32768 + (P) * 16384 + (H) * 8192 + wq * 512);            \
    gload_lds16(yt + ((size_t)(bb * 2048 + tr_ + 64)) * 512 + (KT) * 64 + csw, \
                lds + 32768 + (P) * 16384 + (H) * 8192 + 4096 + wq * 512);     \
  } while (0)

#define MFMA2(MI, NI, A0, A1)                                                  \
    acc[MI][NI] = __builtin_amdgcn_mfma_f32_16x16x32_bf16(A0, br[NI][0],       \
                                                          acc[MI][NI], 0, 0, 0); \
    acc[MI][NI] = __builtin_amdgcn_mfma_f32_16x16x32_bf16(A1, br[NI][1],       \
                                                          acc[MI][NI], 0, 0, 0);

#define PHASE_CORE(Q, READS, STAGES, VWAIT)                                    \
  {                                                                            \
    short8 a00 = FRAG_A(PP, (Q)*2 + 0, 0), a01 = FRAG_A(PP, (Q)*2 + 0, 1);     \
    short8 a10 = FRAG_A(PP, (Q)*2 + 1, 0), a11 = FRAG_A(PP, (Q)*2 + 1, 1);     \
    READS;                                                                     \
    STAGES;                                                                    \
    __builtin_amdgcn_s_barrier();                                              \
    asm volatile("s_waitcnt lgkmcnt(0)" ::: "memory");                         \
    __builtin_amdgcn_sched_barrier(0);                                         \
    __builtin_amdgcn_s_setprio(1);                                             \
    MFMA2((Q)*2 + 0, 0, a00, a01) MFMA2((Q)*2 + 0, 1, a00, a01)                \
    MFMA2((Q)*2 + 0, 2, a00, a01) MFMA2((Q)*2 + 0, 3, a00, a01)                \
    MFMA2((Q)*2 + 1, 0, a10, a11) MFMA2((Q)*2 + 1, 1, a10, a11)                \
    MFMA2((Q)*2 + 1, 2, a10, a11) MFMA2((Q)*2 + 1, 3, a10, a11)                \
    __builtin_amdgcn_s_setprio(0);                                             \
    __builtin_amdgcn_sched_barrier(0);                                         \
    VWAIT;                                                                     \
    __builtin_amdgcn_s_barrier();                                              \
  }

#define READ_B(P) do {                                                         \
    br[0][0] = FRAG_B(P, 0, 0); br[0][1] = FRAG_B(P, 0, 1);                    \
    br[1][0] = FRAG_B(P, 1, 0); br[1][1] = FRAG_B(P, 1, 1);                    \
    br[2][0] = FRAG_B(P, 2, 0); br[2][1] = FRAG_B(P, 2, 1);                    \
    br[3][0] = FRAG_B(P, 3, 0); br[3][1] = FRAG_B(P, 3, 1);                    \
  } while (0)

__global__ __launch_bounds__(512, 2) void gemm_glu(
    const u16* __restrict__ Wb, const u16* __restrict__ yt,
    const float* __restrict__ bias, float* __restrict__ out) {
  extern __shared__ __align__(16) u16 lds[];
  const int bid = blockIdx.x;
  const int wg = (bid & 7) * 64 + (bid >> 3);  // XCD swizzle (512 = 8*64)
  const int bb = wg >> 5;
  const int mt = (wg >> 3) & 3;
  const int nt = wg & 7;
  const int m0 = mt * 256;
  const int t0b = nt * 256;
  const int tid = threadIdx.x;
  const int lane = tid & 63;
  const int wq = tid >> 6;
  const int wq8 = wq * 8, l3 = lane >> 3;
  const int wm = wq >> 2, wn = wq & 3;
  const int lrow = lane & 15, lq = lane >> 4;
  const int csw = ((lane & 7) ^ l3) * 8;
  const int cs0 = ((lq ^ (lane & 7)) << 3);
  const int cs1 = (((4 + lq) ^ (lane & 7)) << 3);
  const int wmh = wm * 8192;
  const int hBh = (wn >> 1) * 8192;
  const int rB = (wn & 1) * 64;

  f32x4 acc[8][4];
  const f32x4 z4 = {0.f, 0.f, 0.f, 0.f};
  #pragma unroll
  for (int mi = 0; mi < 8; ++mi)
    #pragma unroll
    for (int ni = 0; ni < 4; ++ni) acc[mi][ni] = z4;
  short8 br[4][2];

  STAGE_A(0, 0, 0); STAGE_A(0, 1, 0);
  STAGE_B(0, 0, 0); STAGE_B(0, 1, 0);
  STAGE_B(1, 0, 1); STAGE_B(1, 1, 1);
  asm volatile("s_waitcnt vmcnt(4)" ::: "memory");
  __builtin_amdgcn_s_barrier();

  #pragma unroll
  for (int j = 0; j < 4; ++j) {
    const int e2 = 2 * j + 2, o1 = 2 * j + 1, o3 = 2 * j + 3;
    #define PP 0
    PHASE_CORE(0, READ_B(0), STAGE_A(o1, 0, 1), )
    PHASE_CORE(1, , { STAGE_A(o1, 1, 1); if (j < 3) STAGE_B(e2, 0, 0); }, )
    PHASE_CORE(2, , if (j < 3) STAGE_B(e2, 1, 0), )
    PHASE_CORE(3, , ,
               if (j < 3) { asm volatile("s_waitcnt vmcnt(4)" ::: "memory"); }
               else { asm volatile("s_waitcnt vmcnt(0)" ::: "memory"); })
    #undef PP
    #define PP 1
    PHASE_CORE(0, READ_B(1), if (j < 3) STAGE_A(e2, 0, 0), )
    PHASE_CORE(1, , if (j < 3) STAGE_A(e2, 1, 0), )
    PHASE_CORE(2, , if (j < 3) STAGE_B(o3, 0, 1), )
    PHASE_CORE(3, , if (j < 3) STAGE_B(o3, 1, 1),
               if (j < 3) { asm volatile("s_waitcnt vmcnt(4)" ::: "memory"); })
    #undef PP
  }

  #pragma unroll
  for (int mi = 0; mi < 8; ++mi) {
    const int sr0 = m0 + wm * 128 + mi * 16 + lq * 4;
    const int ch = sr0 >> 1;
    const float ba0 = bias[ch],     bg0 = bias[512 + ch];
    const float ba1 = bias[ch + 1], bg1 = bias[512 + ch + 1];
    #pragma unroll
    for (int ni = 0; ni < 4; ++ni) {
      const int t = t0b + wn * 64 + ni * 16 + (lane & 15);
      const f32x4 v = acc[mi][ni];
      const float a0 = v[0] + ba0, g0 = v[1] + bg0;
      const float a1 = v[2] + ba1, g1 = v[3] + bg1;
      out[((size_t)(bb * 512 + ch)) * 2048 + t]     = a0 * RCP(1.f + __expf(-g0));
      out[((size_t)(bb * 512 + ch + 1)) * 2048 + t] = a1 * RCP(1.f + __expf(-g1));
    }
  }
}

extern "C" void kernel_launch(void* const* d_in, const int* in_sizes, int n_in,
                              void* d_out, int out_size, void* d_ws, size_t ws_size,
                              hipStream_t stream) {
  (void)in_sizes; (void)n_in; (void)out_size; (void)ws_size;
  const float* u      = (const float*)d_in[0];
  const float* log_dt = (const float*)d_in[1];
  const float* Hr     = (const float*)d_in[2];
  const float* Hi     = (const float*)d_in[3];
  const float* Dv     = (const float*)d_in[4];
  const float* W      = (const float*)d_in[5];
  const float* bias   = (const float*)d_in[6];

  char* ws = (char*)d_ws;
  float2* kep = (float2*)(ws);                     // 512*513*4*8 = 8.4 MB
  u16*    Wb  = (u16*)  (ws + ((size_t)9 << 20));  // 1 MB
  u16*    yt  = (u16*)  (ws + ((size_t)12 << 20)); // 32 MB
  u16*    ybf = (u16*)d_out;                       // bf16 y staged in d_out[0,32MB)

  build_kep<<<dim3(512), 512, 0, stream>>>(log_dt, Hr, Hi, Dv, W, kep, Wb);
  fft_conv<<<dim3(8, 512), 256, 0, stream>>>(u, kep, ybf);
  transpose_y<<<dim3(32, 8, 16), 256, 0, stream>>>(ybf, yt);
  gemm_glu<<<dim3(512), 512, 131072, stream>>>(Wb, yt, bias, (float*)d_out);
}

// Round 16
// 124.295 us; speedup vs baseline: 1.0389x; 1.0068x over previous
//
#include <hip/hip_runtime.h>
#include <math.h>

typedef unsigned short u16;
typedef unsigned int u32;
typedef __attribute__((ext_vector_type(8))) short short8;
typedef __attribute__((ext_vector_type(8))) u16 u16x8;
typedef __attribute__((ext_vector_type(4))) float f32x4;

// XOR swizzle: bijective within 1024, spreads 16-stride clusters across
// 16 16B-slots (verified per access family in R15; measured conflicts 3.4e6).
#define SW(i) ((i) ^ (((i) >> 4) & 15))

#if __has_builtin(__builtin_amdgcn_rcpf)
#define RCP(x) __builtin_amdgcn_rcpf(x)
#else
#define RCP(x) (1.0f / (x))
#endif

// LDS-only barrier (T4): drain lgkmcnt, barrier, pin scheduling.
#define LBAR()                                                                 \
  do {                                                                         \
    asm volatile("s_waitcnt lgkmcnt(0)" ::: "memory");                         \
    __builtin_amdgcn_s_barrier();                                              \
    __builtin_amdgcn_sched_barrier(0);                                         \
  } while (0)

static __device__ __forceinline__ u16 f2bf(float x) {
  unsigned u = __builtin_bit_cast(unsigned, x);
  return (u16)((u + 0x7FFFu + ((u >> 16) & 1u)) >> 16);
}

static __device__ __forceinline__ float2 cmul(float2 a, float2 b) {
  return make_float2(a.x * b.x - a.y * b.y, a.x * b.y + a.y * b.x);
}
static __device__ __forceinline__ float2 cadd(float2 a, float2 b) {
  return make_float2(a.x + b.x, a.y + b.y);
}
static __device__ __forceinline__ float2 conjf2(float2 a) {
  return make_float2(a.x, -a.y);
}
static __device__ __forceinline__ float2 mkC(float a, float b) {
  return make_float2(a, b);
}
// pack both rows' complex values into one float4 LDS slot
static __device__ __forceinline__ float4 pk2(float2 p, float2 q) {
  return make_float4(p.x, p.y, q.x, q.y);
}

// W_1024^j = e^{-2pi i j/1024}, computed on the fly
static __device__ __forceinline__ float2 twd(int j) {
  float s, c;
  __sincosf((float)j * -0.00613592315154256492f, &s, &c);
  return make_float2(c, s);
}

// tanh-form GELU: y * sigmoid(1.59577*(y + 0.044715 y^3)); max dev ~1e-3
static __device__ __forceinline__ float gelu_fast(float y) {
  const float t = __builtin_fmaf(0.044715f * y * y, y, y);
  const float e = __expf(-1.5957691216f * t);
  return y * RCP(1.f + e);
}

static __device__ __forceinline__ u32 pack_out(float2 r) {
  const u32 lo = f2bf(gelu_fast(r.x));
  const u32 hi = f2bf(gelu_fast(-r.y));
  return lo | (hi << 16);
}

// async global->LDS, 16B per lane
static __device__ __forceinline__ void gload_lds16(const void* g, void* l) {
  __builtin_amdgcn_global_load_lds(
      (const __attribute__((address_space(1))) u32*)g,
      (__attribute__((address_space(3))) u32*)l, 16, 0, 0);
}

#define BF4(A, B, C, D, Y0, Y1, Y2, Y3)                                        \
  {                                                                            \
    const float apcr = (A).x + (C).x, apci = (A).y + (C).y;                    \
    const float amcr = (A).x - (C).x, amci = (A).y - (C).y;                    \
    const float bpdr = (B).x + (D).x, bpdi = (B).y + (D).y;                    \
    const float bmdr = (B).x - (D).x, bmdi = (B).y - (D).y;                    \
    Y0 = make_float2(apcr + bpdr, apci + bpdi);                                \
    Y2 = make_float2(apcr - bpdr, apci - bpdi);                                \
    Y1 = make_float2(amcr + bmdi, amci - bmdr);                                \
    Y3 = make_float2(amcr - bmdi, amci + bmdr);                                \
  }

// ---------------- K1: merged hope-kernel + filter coeffs (+D folded) + W->bf16
static __device__ __forceinline__ void hope_sum(
    const float* __restrict__ log_dt, const float* __restrict__ Hr,
    const float* __restrict__ Hi, int h, int l, float* outr, float* outi) {
  const float dt = expf(log_dt[h]);
  const float phi = 6.28318530717958647692f * (float)l * (1.0f / 1024.0f);
  float sphi, cphi;
  sincosf(phi, &sphi, &cphi);
  const float nr = (1.f + dt) * cphi + dt - 1.f;
  const float ni = (1.f + dt) * sphi;
  const float dr = (dt - 1.f) * cphi + dt + 1.f;
  const float di = (dt - 1.f) * sphi;
  const float theta = atan2f(ni * dr - nr * di, nr * dr + ni * di);
  float sw, cw;
  sincosf(theta, &sw, &cw);
  const float wr = cw, wi = -sw;  // e^{-i theta}
  float cr = wr, ci = wi;
  float ar = 0.f, ai = 0.f;
  const float* __restrict__ hr = Hr + h * 64;
  const float* __restrict__ hi = Hi + h * 64;
  for (int n = 0; n < 64; ++n) {
    const float a = hr[n], bb = hi[n];
    ar += a * cr - bb * ci;
    ai += a * ci + bb * cr;
    const float t = cr * wr - ci * wi;
    ci = cr * wi + ci * wr;
    cr = t;
  }
  *outr = ar;
  *outi = ai;
}

__global__ __launch_bounds__(512) void build_kep(
    const float* __restrict__ log_dt, const float* __restrict__ Hr,
    const float* __restrict__ Hi, const float* __restrict__ Dv,
    const float* __restrict__ W, float2* __restrict__ kep,
    u16* __restrict__ Wb) {
  __shared__ float2 K1[1024], K2[1024];
  const int c = blockIdx.x;
  const int t = threadIdx.x;
  // fold conv_w in: block c converts W[c*1024 .. c*1024+1024)
  Wb[c * 1024 + t] = f2bf(W[c * 1024 + t]);
  Wb[c * 1024 + 512 + t] = f2bf(W[c * 1024 + 512 + t]);
  float r, i;
  hope_sum(log_dt, Hr, Hi, c, t, &r, &i);             K1[t] = make_float2(r, i);
  hope_sum(log_dt, Hr, Hi, c, t + 512, &r, &i);       K1[t + 512] = make_float2(r, i);
  hope_sum(log_dt, Hr, Hi, c + 512, t, &r, &i);       K2[t] = make_float2(r, i);
  hope_sum(log_dt, Hr, Hi, c + 512, t + 512, &r, &i); K2[t + 512] = make_float2(r, i);
  __syncthreads();
  const float s = 1.0f / 2048.0f;   // fold ifft scale (exact)
  const float dcs = Dv[c] * s;      // fold D-skip: k'[f] = k[f] + D[c]
  for (int q = t; q <= 512; q += 512) {  // t==0 also covers q=512
    float2 kf, kg;
    {
      const int qa = q;
      kf = (qa == 0) ? make_float2(K1[0].x * s, 0.f)
                     : make_float2(0.5f * s * (K1[qa].x + K2[qa - 1].x),
                                   0.5f * s * (K1[qa].y - K2[qa - 1].y));
      const int qb = 1024 - q;
      kg = (qb == 1024) ? make_float2(K2[1023].x * s, 0.f)
           : (qb == 0)  ? make_float2(K1[0].x * s, 0.f)
                        : make_float2(0.5f * s * (K1[qb].x + K2[qb - 1].x),
                                      0.5f * s * (K1[qb].y - K2[qb - 1].y));
    }
    kf.x += dcs;
    kg.x += dcs;
    float2 C1, C2, C3, C4;
    if (q == 0) {
      C1 = make_float2(kf.x + kg.x, kg.y - kf.y);
      C2 = make_float2(-(kg.y + kf.y), kg.x - kf.x);
      C3 = C2;
      C4 = C1;
    } else {
      float st, ct;
      sincosf(3.14159265358979323846f * (float)q * (1.f / 1024.f), &st, &ct);
      const float2 A1 = make_float2(1.f - st, -ct);
      const float2 A2 = make_float2(1.f + st, ct);
      const float2 kgc = make_float2(kg.x, -kg.y);
      const float2 t1 = cmul(kf, A1), t2 = cmul(kgc, A2);
      const float2 t3 = cmul(kf, A2), t4 = cmul(kgc, A1);
      const float2 p1 = make_float2(0.5f * (t1.x + t2.x), 0.5f * (t1.y + t2.y));
      const float2 p2 = make_float2(0.5f * (t3.x + t4.x), 0.5f * (t3.y + t4.y));
      const float2 q1 = make_float2(0.5f * (t1.x - t2.x), 0.5f * (t1.y - t2.y));
      const float2 q2 = make_float2(0.5f * (t3.x - t4.x), 0.5f * (t3.y - t4.y));
      const float2 iWc = make_float2(-st, ct);
      const float2 r1 = cmul(iWc, q1), r2 = cmul(iWc, q2);
      C1 = make_float2(p1.x + r1.x, -(p1.y + r1.y));
      C2 = make_float2(p2.x + r2.x, -(p2.y + r2.y));
      C3 = make_float2(p1.x - r1.x, p1.y - r1.y);
      C4 = make_float2(p2.x - r2.x, p2.y - r2.y);
    }
    float2* o = kep + ((size_t)c * 513 + q) * 4;
    o[0] = C1; o[1] = C2; o[2] = C3; o[3] = C4;
  }
}

// ------- K2: Stockham rfft-conv, 2 rows interleaved per float4 LDS slot -------
// slot[i] = (row0.re, row0.im, row1.re, row1.im) -> 8 b128 R + 8 b128 W /stage.
static __device__ __forceinline__ void stage_pair(
    const float4* __restrict__ S, float4* __restrict__ D, int t, int sh) {
  const int m = 1 << sh;
  const int kk = t & (m - 1);
  const int o = kk + ((t >> sh) << (sh + 2));
  const float4 va = S[SW(t)];
  const float4 vb = S[SW(t + 256)];
  const float4 vc = S[SW(t + 512)];
  const float4 vd = S[SW(t + 768)];
  const float2 a0 = mkC(va.x, va.y), a1 = mkC(va.z, va.w);
  const float2 b0 = mkC(vb.x, vb.y), b1 = mkC(vb.z, vb.w);
  const float2 c0 = mkC(vc.x, vc.y), c1 = mkC(vc.z, vc.w);
  const float2 d0 = mkC(vd.x, vd.y), d1 = mkC(vd.z, vd.w);
  float2 x0, x1, x2, x3, z0, z1, z2, z3;
  BF4(a0, b0, c0, d0, x0, x1, x2, x3);
  BF4(a1, b1, c1, d1, z0, z1, z2, z3);
  const float2 w1 = twd((t >> sh) << sh);
  const float2 w2 = cmul(w1, w1);
  const float2 w3 = cmul(w2, w1);
  D[SW(o)] = pk2(x0, z0);
  D[SW(o + m)] = pk2(cmul(w1, x1), cmul(w1, z1));
  D[SW(o + 2 * m)] = pk2(cmul(w2, x2), cmul(w2, z2));
  D[SW(o + 3 * m)] = pk2(cmul(w3, x3), cmul(w3, z3));
}

// Last stage (sh=8): twiddle-free, natural-order writes (FFT#1 result Z).
static __device__ __forceinline__ void stage_pair_last(
    const float4* __restrict__ S, float4* __restrict__ D, int t) {
  const float4 va = S[SW(t)];
  const float4 vb = S[SW(t + 256)];
  const float4 vc = S[SW(t + 512)];
  const float4 vd = S[SW(t + 768)];
  const float2 a0 = mkC(va.x, va.y), a1 = mkC(va.z, va.w);
  const float2 b0 = mkC(vb.x, vb.y), b1 = mkC(vb.z, vb.w);
  const float2 c0 = mkC(vc.x, vc.y), c1 = mkC(vc.z, vc.w);
  const float2 d0 = mkC(vd.x, vd.y), d1 = mkC(vd.z, vd.w);
  float2 x0, x1, x2, x3, z0, z1, z2, z3;
  BF4(a0, b0, c0, d0, x0, x1, x2, x3);
  BF4(a1, b1, c1, d1, z0, z1, z2, z3);
  D[SW(t)] = pk2(x0, z0);
  D[SW(t + 256)] = pk2(x1, z1);
  D[SW(t + 512)] = pk2(x2, z2);
  D[SW(t + 768)] = pk2(x3, z3);
}

__global__ __launch_bounds__(256) void fft_conv(
    const float* __restrict__ u, const float2* __restrict__ kep,
    u16* __restrict__ y) {
  __shared__ float4 bufA[1024], bufB[1024];  // 32768 B exactly
  const int bq = blockIdx.x, c = blockIdx.y;
  const int t = threadIdx.x;

  // prefetch filter coefficients (stay in flight across LDS-only barriers)
  const float4* __restrict__ krow4 = (const float4*)(kep + (size_t)c * (513 * 4));
  const float4 cA0 = krow4[2 * t];               // C1C2(q=t)
  const float4 cA1 = krow4[2 * (t + 256)];       // C1C2(q=t+256)
  const float4 cC  = krow4[2 * (512 - t) + 1];   // C3C4(q=512-t)
  const float4 cDq = krow4[2 * (256 - t) + 1];   // C3C4(q=256-t)
  const float4 cM  = krow4[1024];                // C1C2(q=512), used iff t==0

  const int b0 = bq * 2, b1 = bq * 2 + 1;
  const float2* __restrict__ u20 = (const float2*)(u + ((size_t)(b0 * 512 + c)) * 2048);
  const float2* __restrict__ u21 = (const float2*)(u + ((size_t)(b1 * 512 + c)) * 2048);
  u32* __restrict__ yr0 = (u32*)(y + ((size_t)(b0 * 512 + c)) * 2048);
  u32* __restrict__ yr1 = (u32*)(y + ((size_t)(b1 * 512 + c)) * 2048);
  float4* A = bufA;
  float4* B = bufB;

  // ---- FFT #1, stage 0 (sh=0) from registers: z[p]=u[2p]+i*u[2p+1] ----
  {
    float2 v0[4], v1[4];
    #pragma unroll
    for (int q = 0; q < 4; ++q) {
      v0[q] = u20[t + 256 * q];
      v1[q] = u21[t + 256 * q];
    }
    float2 x0, x1, x2, x3, z0, z1, z2, z3;
    BF4(v0[0], v0[1], v0[2], v0[3], x0, x1, x2, x3);
    BF4(v1[0], v1[1], v1[2], v1[3], z0, z1, z2, z3);
    const float2 w1 = twd(t);
    const float2 w2 = cmul(w1, w1);
    const float2 w3 = cmul(w2, w1);
    const int o = 4 * t;
    A[SW(o)] = pk2(x0, z0);
    A[SW(o + 1)] = pk2(cmul(w1, x1), cmul(w1, z1));
    A[SW(o + 2)] = pk2(cmul(w2, x2), cmul(w2, z2));
    A[SW(o + 3)] = pk2(cmul(w3, x3), cmul(w3, z3));
  }
  LBAR();
  stage_pair(A, B, t, 2); LBAR();
  stage_pair(B, A, t, 4); LBAR();
  stage_pair(A, B, t, 6); LBAR();
  stage_pair_last(B, A, t); LBAR();  // Z in A (natural order)

  // ---- fused filter + FFT#2 stage 0 (A -> B, conj trick) ----
  {
    const int gp0 = (1024 - t) & 1023;
    const float2 w1 = twd(t);
    const float2 w2 = cmul(w1, w1);
    const float2 w3 = cmul(w2, w1);
    const int o = 4 * t;
    const float4 Vf0 = A[SW(t)],       Vg0 = A[SW(gp0)];
    const float4 Vf1 = A[SW(t + 256)], Vg1 = A[SW(768 - t)];
    const float4 Vc  = A[SW(t + 512)], Vcf = A[SW(512 - t)];
    const float4 Vd  = A[SW(t + 768)], Vdf = A[SW(256 - t)];
    const float2 CA1 = mkC(cA0.x, cA0.y), CA2 = mkC(cA0.z, cA0.w);
    const float2 CB1 = mkC(cA1.x, cA1.y), CB2 = mkC(cA1.z, cA1.w);
    const float2 CC3 = mkC(cC.x, cC.y),   CC4 = mkC(cC.z, cC.w);
    const float2 CD3 = mkC(cDq.x, cDq.y), CD4 = mkC(cDq.z, cDq.w);
    const float2 CM1 = mkC(cM.x, cM.y),   CM2 = mkC(cM.z, cM.w);
    float2 Da0, Da1, Db0, Db1, Dc0, Dc1, Dd0, Dd1;
    // row0 from .xy, row1 from .zw
    Da0 = cadd(cmul(CA1, conjf2(mkC(Vf0.x, Vf0.y))), cmul(CA2, mkC(Vg0.x, Vg0.y)));
    Da1 = cadd(cmul(CA1, conjf2(mkC(Vf0.z, Vf0.w))), cmul(CA2, mkC(Vg0.z, Vg0.w)));
    Db0 = cadd(cmul(CB1, conjf2(mkC(Vf1.x, Vf1.y))), cmul(CB2, mkC(Vg1.x, Vg1.y)));
    Db1 = cadd(cmul(CB1, conjf2(mkC(Vf1.z, Vf1.w))), cmul(CB2, mkC(Vg1.z, Vg1.w)));
    if (t == 0) {
      Dc0 = cadd(cmul(CM1, conjf2(mkC(Vc.x, Vc.y))), cmul(CM2, mkC(Vc.x, Vc.y)));
      Dc1 = cadd(cmul(CM1, conjf2(mkC(Vc.z, Vc.w))), cmul(CM2, mkC(Vc.z, Vc.w)));
    } else {
      Dc0 = cadd(cmul(CC3, mkC(Vcf.x, Vcf.y)), cmul(CC4, conjf2(mkC(Vc.x, Vc.y))));
      Dc1 = cadd(cmul(CC3, mkC(Vcf.z, Vcf.w)), cmul(CC4, conjf2(mkC(Vc.z, Vc.w))));
    }
    Dd0 = cadd(cmul(CD3, mkC(Vdf.x, Vdf.y)), cmul(CD4, conjf2(mkC(Vd.x, Vd.y))));
    Dd1 = cadd(cmul(CD3, mkC(Vdf.z, Vdf.w)), cmul(CD4, conjf2(mkC(Vd.z, Vd.w))));
    float2 x0, x1, x2, x3, z0, z1, z2, z3;
    BF4(Da0, Db0, Dc0, Dd0, x0, x1, x2, x3);
    BF4(Da1, Db1, Dc1, Dd1, z0, z1, z2, z3);
    B[SW(o)] = pk2(x0, z0);
    B[SW(o + 1)] = pk2(cmul(w1, x1), cmul(w1, z1));
    B[SW(o + 2)] = pk2(cmul(w2, x2), cmul(w2, z2));
    B[SW(o + 3)] = pk2(cmul(w3, x3), cmul(w3, z3));
  }
  LBAR();

  // ---- FFT #2 remaining stages, last stage to registers ----
  stage_pair(B, A, t, 2); LBAR();
  stage_pair(A, B, t, 4); LBAR();
  stage_pair(B, A, t, 6); LBAR();
  {
    const float4 va = A[SW(t)];
    const float4 vb = A[SW(t + 256)];
    const float4 vc = A[SW(t + 512)];
    const float4 vd = A[SW(t + 768)];
    const float2 pa0 = mkC(va.x, va.y), pa1 = mkC(va.z, va.w);
    const float2 pb0 = mkC(vb.x, vb.y), pb1 = mkC(vb.z, vb.w);
    const float2 pc0 = mkC(vc.x, vc.y), pc1 = mkC(vc.z, vc.w);
    const float2 pd0 = mkC(vd.x, vd.y), pd1 = mkC(vd.z, vd.w);
    float2 x0, x1, x2, x3, z0, z1, z2, z3;
    BF4(pa0, pb0, pc0, pd0, x0, x1, x2, x3);
    BF4(pa1, pb1, pc1, pd1, z0, z1, z2, z3);
    // point p = t + 256r -> output word p (2 bf16); D-skip folded into kep
    yr0[t] = pack_out(x0);       yr1[t] = pack_out(z0);
    yr0[t + 256] = pack_out(x1); yr1[t + 256] = pack_out(z1);
    yr0[t + 512] = pack_out(x2); yr1[t + 512] = pack_out(z2);
    yr0[t + 768] = pack_out(x3); yr1[t + 768] = pack_out(z3);
  }
}

// ---------------- K2b: y (B,C,L) bf16 -> yt (B,L,C) bf16 ----------------
__global__ __launch_bounds__(256) void transpose_y(
    const u16* __restrict__ y, u16* __restrict__ yt) {
  __shared__ u16 tile[64][80];
  const int b = blockIdx.z;
  const int tb = blockIdx.x * 64;
  const int cb = blockIdx.y * 64;
  const int tid = threadIdx.x;
  {
    const int tl = (tid & 7) * 8;
    const int cl = tid >> 3;
    #pragma unroll
    for (int h = 0; h < 2; ++h) {
      const int cc = cl + h * 32;
      const u16x8 v = *(const u16x8*)(y + ((size_t)(b * 512 + cb + cc)) * 2048 + tb + tl);
      #pragma unroll
      for (int i = 0; i < 8; ++i) tile[cc][tl + i] = v[i];
    }
  }
  __syncthreads();
  {
    const int c2 = (tid & 7) * 8;
    const int t2 = tid >> 3;
    #pragma unroll
    for (int h = 0; h < 2; ++h) {
      const int tt = t2 + h * 32;
      u16 tmp[8];
      #pragma unroll
      for (int i = 0; i < 8; ++i) tmp[i] = tile[c2 + i][tt];
      *(u16x8*)(yt + ((size_t)(b * 2048 + tb + tt)) * 512 + cb + c2) = *(u16x8*)tmp;
    }
  }
}

// ---------------- K3: 256x256x(K=512) 8-phase GEMM + GLU ----------------
#define FRAG_A(P, MI, S) __builtin_bit_cast(short8, *(const u16x8*)&lds[       \
    (P) * 16384 + wmh + ((MI) * 16 + lrow) * 64 + ((S) ? cs1 : cs0)])
#define FRAG_B(P, NI, S) __builtin_bit_cast(short8, *(const u16x8*)&lds[       \
    32768 + (P) * 16384 + hBh + (rB + (NI) * 16 + lrow) * 64 + ((S) ? cs1 : cs0)])

#define STAGE_A(KT, H, P) do {                                                 \
    int sr_ = m0 + (H) * 128 + wq8 + l3;                                       \
    int o0_ = (sr_ & 1) ? (512 + (sr_ >> 1)) : (sr_ >> 1);                     \
    gload_lds16(Wb + (size_t)o0_ * 512 + (KT) * 64 + csw,                      \
                lds + (P) * 16384 + (H) * 8192 + wq * 512);                    \
    sr_ += 64;                                                                 \
    int o1_ = (sr_ & 1) ? (512 + (sr_ >> 1)) : (sr_ >> 1);                     \
    gload_lds16(Wb + (size_t)o1_ * 512 + (KT) * 64 + csw,                      \
                lds + (P) * 16384 + (H) * 8192 + 4096 + wq * 512);             \
  } while (0)
#define STAGE_B(KT, H, P) do {                                                 \
    int tr_ = t0b + (H) * 128 + wq8 + l3;                                      \
    gload_lds16(yt + ((size_t)(bb * 2048 + tr_)) * 512 + (KT) * 64 + csw,      \
                lds + 32768 + (P) * 16384 + (H) * 8192 + wq * 512);            \
    gload_lds16(yt + ((size_t)(bb * 2048 + tr_ + 64)) * 512 + (KT) * 64 + csw, \
                lds + 32768 + (P) * 16384 + (H) * 8192 + 4096 + wq * 512);     \
  } while (0)

#define MFMA2(MI, NI, A0, A1)                                                  \
    acc[MI][NI] = __builtin_amdgcn_mfma_f32_16x16x32_bf16(A0, br[NI][0],       \
                                                          acc[MI][NI], 0, 0, 0); \
    acc[MI][NI] = __builtin_amdgcn_mfma_f32_16x16x32_bf16(A1, br[NI][1],       \
                                                          acc[MI][NI], 0, 0, 0);

#define PHASE_CORE(Q, READS, STAGES, VWAIT)                                    \
  {                                                                            \
    short8 a00 = FRAG_A(PP, (Q)*2 + 0, 0), a01 = FRAG_A(PP, (Q)*2 + 0, 1);     \
    short8 a10 = FRAG_A(PP, (Q)*2 + 1, 0), a11 = FRAG_A(PP, (Q)*2 + 1, 1);     \
    READS;                                                                     \
    STAGES;                                                                    \
    __builtin_amdgcn_s_barrier();                                              \
    asm volatile("s_waitcnt lgkmcnt(0)" ::: "memory");                         \
    __builtin_amdgcn_sched_barrier(0);                                         \
    __builtin_amdgcn_s_setprio(1);                                             \
    MFMA2((Q)*2 + 0, 0, a00, a01) MFMA2((Q)*2 + 0, 1, a00, a01)                \
    MFMA2((Q)*2 + 0, 2, a00, a01) MFMA2((Q)*2 + 0, 3, a00, a01)                \
    MFMA2((Q)*2 + 1, 0, a10, a11) MFMA2((Q)*2 + 1, 1, a10, a11)                \
    MFMA2((Q)*2 + 1, 2, a10, a11) MFMA2((Q)*2 + 1, 3, a10, a11)                \
    __builtin_amdgcn_s_setprio(0);                                             \
    __builtin_amdgcn_sched_barrier(0);                                         \
    VWAIT;                                                                     \
    __builtin_amdgcn_s_barrier();                                              \
  }

#define READ_B(P) do {                                                         \
    br[0][0] = FRAG_B(P, 0, 0); br[0][1] = FRAG_B(P, 0, 1);                    \
    br[1][0] = FRAG_B(P, 1, 0); br[1][1] = FRAG_B(P, 1, 1);                    \
    br[2][0] = FRAG_B(P, 2, 0); br[2][1] = FRAG_B(P, 2, 1);                    \
    br[3][0] = FRAG_B(P, 3, 0); br[3][1] = FRAG_B(P, 3, 1);                    \
  } while (0)

__global__ __launch_bounds__(512, 2) void gemm_glu(
    const u16* __restrict__ Wb, const u16* __restrict__ yt,
    const float* __restrict__ bias, float* __restrict__ out) {
  extern __shared__ __align__(16) u16 lds[];
  const int bid = blockIdx.x;
  const int wg = (bid & 7) * 64 + (bid >> 3);  // XCD swizzle (512 = 8*64)
  const int bb = wg >> 5;
  const int mt = (wg >> 3) & 3;
  const int nt = wg & 7;
  const int m0 = mt * 256;
  const int t0b = nt * 256;
  const int tid = threadIdx.x;
  const int lane = tid & 63;
  const int wq = tid >> 6;
  const int wq8 = wq * 8, l3 = lane >> 3;
  const int wm = wq >> 2, wn = wq & 3;
  const int lrow = lane & 15, lq = lane >> 4;
  const int csw = ((lane & 7) ^ l3) * 8;
  const int cs0 = ((lq ^ (lane & 7)) << 3);
  const int cs1 = (((4 + lq) ^ (lane & 7)) << 3);
  const int wmh = wm * 8192;
  const int hBh = (wn >> 1) * 8192;
  const int rB = (wn & 1) * 64;

  f32x4 acc[8][4];
  const f32x4 z4 = {0.f, 0.f, 0.f, 0.f};
  #pragma unroll
  for (int mi = 0; mi < 8; ++mi)
    #pragma unroll
    for (int ni = 0; ni < 4; ++ni) acc[mi][ni] = z4;
  short8 br[4][2];

  STAGE_A(0, 0, 0); STAGE_A(0, 1, 0);
  STAGE_B(0, 0, 0); STAGE_B(0, 1, 0);
  STAGE_B(1, 0, 1); STAGE_B(1, 1, 1);
  asm volatile("s_waitcnt vmcnt(4)" ::: "memory");
  __builtin_amdgcn_s_barrier();

  #pragma unroll
  for (int j = 0; j < 4; ++j) {
    const int e2 = 2 * j + 2, o1 = 2 * j + 1, o3 = 2 * j + 3;
    #define PP 0
    PHASE_CORE(0, READ_B(0), STAGE_A(o1, 0, 1), )
    PHASE_CORE(1, , { STAGE_A(o1, 1, 1); if (j < 3) STAGE_B(e2, 0, 0); }, )
    PHASE_CORE(2, , if (j < 3) STAGE_B(e2, 1, 0), )
    PHASE_CORE(3, , ,
               if (j < 3) { asm volatile("s_waitcnt vmcnt(4)" ::: "memory"); }
               else { asm volatile("s_waitcnt vmcnt(0)" ::: "memory"); })
    #undef PP
    #define PP 1
    PHASE_CORE(0, READ_B(1), if (j < 3) STAGE_A(e2, 0, 0), )
    PHASE_CORE(1, , if (j < 3) STAGE_A(e2, 1, 0), )
    PHASE_CORE(2, , if (j < 3) STAGE_B(o3, 0, 1), )
    PHASE_CORE(3, , if (j < 3) STAGE_B(o3, 1, 1),
               if (j < 3) { asm volatile("s_waitcnt vmcnt(4)" ::: "memory"); })
    #undef PP
  }

  #pragma unroll
  for (int mi = 0; mi < 8; ++mi) {
    const int sr0 = m0 + wm * 128 + mi * 16 + lq * 4;
    const int ch = sr0 >> 1;
    const float ba0 = bias[ch],     bg0 = bias[512 + ch];
    const float ba1 = bias[ch + 1], bg1 = bias[512 + ch + 1];
    #pragma unroll
    for (int ni = 0; ni < 4; ++ni) {
      const int t = t0b + wn * 64 + ni * 16 + (lane & 15);
      const f32x4 v = acc[mi][ni];
      const float a0 = v[0] + ba0, g0 = v[1] + bg0;
      const float a1 = v[2] + ba1, g1 = v[3] + bg1;
      out[((size_t)(bb * 512 + ch)) * 2048 + t]     = a0 * RCP(1.f + __expf(-g0));
      out[((size_t)(bb * 512 + ch + 1)) * 2048 + t] = a1 * RCP(1.f + __expf(-g1));
    }
  }
}

extern "C" void kernel_launch(void* const* d_in, const int* in_sizes, int n_in,
                              void* d_out, int out_size, void* d_ws, size_t ws_size,
                              hipStream_t stream) {
  (void)in_sizes; (void)n_in; (void)out_size; (void)ws_size;
  const float* u      = (const float*)d_in[0];
  const float* log_dt = (const float*)d_in[1];
  const float* Hr     = (const float*)d_in[2];
  const float* Hi     = (const float*)d_in[3];
  const float* Dv     = (const float*)d_in[4];
  const float* W      = (const float*)d_in[5];
  const float* bias   = (const float*)d_in[6];

  char* ws = (char*)d_ws;
  float2* kep = (float2*)(ws);                     // 512*513*4*8 = 8.4 MB
  u16*    Wb  = (u16*)  (ws + ((size_t)9 << 20));  // 1 MB
  u16*    yt  = (u16*)  (ws + ((size_t)12 << 20)); // 32 MB
  u16*    ybf = (u16*)d_out;                       // bf16 y staged in d_out[0,32MB)

  build_kep<<<dim3(512), 512, 0, stream>>>(log_dt, Hr, Hi, Dv, W, kep, Wb);
  fft_conv<<<dim3(8, 512), 256, 0, stream>>>(u, kep, ybf);
  transpose_y<<<dim3(32, 8, 16), 256, 0, stream>>>(ybf, yt);
  gemm_glu<<<dim3(512), 512, 131072, stream>>>(Wb, yt, bias, (float*)d_out);
}